// Round 6
// baseline (1089.508 us; speedup 1.0000x reference)
//
#include <hip/hip_runtime.h>
#include <hip/hip_bf16.h>

using bf16 = __hip_bfloat16;

typedef __bf16 bf16x8 __attribute__((ext_vector_type(8)));
typedef float  f32x4  __attribute__((ext_vector_type(4)));
typedef unsigned int u32x4 __attribute__((ext_vector_type(4)));
typedef unsigned long long u64;
typedef unsigned short u16;
typedef unsigned int u32;

__device__ __forceinline__ float b2f(bf16 v) { return __bfloat162float(v); }
__device__ __forceinline__ bf16  f2b(float v) { return __float2bfloat16(v); }
__device__ __forceinline__ u16   bits(bf16 v) { return __builtin_bit_cast(u16, v); }

// ---------------------------------------------------------------------------
// Workspace layout
// ---------------------------------------------------------------------------
static constexpr size_t SZ_WD1S = 512ull  * 8192  * 2;  // bf16 [512][128 kg][hi32|lo32]
static constexpr size_t SZ_WD2S = 256ull  * 1536  * 2;  // bf16 [256][3*512] split3
static constexpr size_t SZ_WFUS = 128ull  * 768   * 2;  // bf16 [128][3*256] (Wd3@Win fused, split3)
static constexpr size_t SZ_WU1T = 256ull  * 128   * 2;
static constexpr size_t SZ_WU2T = 512ull  * 256   * 2;
static constexpr size_t SZ_WU3T = 4096ull * 512   * 2;
static constexpr size_t SZ_H1S  = 8192ull * 1536  * 2;  // bf16 [8192][3*512] (hi,hi,lo)
static constexpr size_t SZ_H2S  = 8192ull * 768   * 2;  // bf16 [8192][3*256]
static constexpr size_t SZ_XE   = 8192ull * 128   * 4;  // f32 xe (cols e*32+c, 96..127 unused)
static constexpr size_t SZ_QEMB = 3ull * 8192 * 128 * 4;// f32
static constexpr size_t SZ_RL   = 8192ull * 128   * 2;  // bf16
static constexpr size_t SZ_U1   = 8192ull * 256   * 2;
static constexpr size_t SZ_U2   = 8192ull * 512   * 2;
static constexpr size_t SZ_CNRM = 768ull * 4;
static constexpr size_t SZ_BFUS = 128ull * 4;
static constexpr size_t SZ_PART = 4ull * 8192 * 512 * 4; // f32 K-split partials (4 slabs)

static constexpr size_t OFF_WD1S = 0;
static constexpr size_t OFF_WD2S = OFF_WD1S + SZ_WD1S;
static constexpr size_t OFF_WFUS = OFF_WD2S + SZ_WD2S;
static constexpr size_t OFF_WU1T = OFF_WFUS + SZ_WFUS;
static constexpr size_t OFF_WU2T = OFF_WU1T + SZ_WU1T;
static constexpr size_t OFF_WU3T = OFF_WU2T + SZ_WU2T;
static constexpr size_t OFF_H1S  = OFF_WU3T + SZ_WU3T;
static constexpr size_t OFF_H2S  = OFF_H1S  + SZ_H1S;
static constexpr size_t OFF_XE   = OFF_H2S  + SZ_H2S;
static constexpr size_t OFF_QEMB = OFF_XE   + SZ_XE;
static constexpr size_t OFF_RL   = OFF_QEMB + SZ_QEMB;
static constexpr size_t OFF_U1   = OFF_RL   + SZ_RL;
static constexpr size_t OFF_U2   = OFF_U1   + SZ_U1;
static constexpr size_t OFF_CNRM = OFF_U2   + SZ_U2;
static constexpr size_t OFF_BFUS = OFF_CNRM + ((SZ_CNRM + 255) & ~size_t(255));
static constexpr size_t OFF_STAT = OFF_BFUS + ((SZ_BFUS + 255) & ~size_t(255));
// stats (memset 0 each launch): +0 f32 commit; +8 double gram[6]; +64 f32 meanAcc[384]
static constexpr size_t OFF_PART = OFF_STAT + 2048;

// ---------------------------------------------------------------------------
// Weight transposes: in [K][N] f32.
// ---------------------------------------------------------------------------
__global__ void wtrans_bf16(const float* __restrict__ in, bf16* __restrict__ out,
                            int K, int N)
{
    __shared__ float tile[32][33];
    const int tx = threadIdx.x, ty = threadIdx.y;
    const int n0 = blockIdx.x * 32, k0 = blockIdx.y * 32;
    #pragma unroll
    for (int i = 0; i < 32; i += 8)
        tile[ty + i][tx] = in[(size_t)(k0 + ty + i) * N + n0 + tx];
    __syncthreads();
    #pragma unroll
    for (int i = 0; i < 32; i += 8)
        out[(size_t)(n0 + ty + i) * K + k0 + tx] = f2b(tile[tx][ty + i]);
}

__global__ void wtrans_split3(const float* __restrict__ in, bf16* __restrict__ out,
                              int K, int N)
{
    __shared__ float tile[32][33];
    const int tx = threadIdx.x, ty = threadIdx.y;
    const int n0 = blockIdx.x * 32, k0 = blockIdx.y * 32;
    #pragma unroll
    for (int i = 0; i < 32; i += 8)
        tile[ty + i][tx] = in[(size_t)(k0 + ty + i) * N + n0 + tx];
    __syncthreads();
    #pragma unroll
    for (int i = 0; i < 32; i += 8) {
        const float v = tile[tx][ty + i];
        const bf16 hi = f2b(v);
        const bf16 lo = f2b(v - b2f(hi));
        bf16* o = out + (size_t)(n0 + ty + i) * 3 * K + 3 * (k0 + tx);
        o[0] = hi; o[1] = lo; o[2] = hi;
    }
}

// Wd1 -> [n 0..511][kg 0..127][slot: hi k&31 | 32+ lo k&31]
__global__ void wtrans_hilo(const float* __restrict__ in, bf16* __restrict__ out,
                            int K, int N)
{
    __shared__ float tile[32][33];
    const int tx = threadIdx.x, ty = threadIdx.y;
    const int n0 = blockIdx.x * 32, k0 = blockIdx.y * 32;
    #pragma unroll
    for (int i = 0; i < 32; i += 8)
        tile[ty + i][tx] = in[(size_t)(k0 + ty + i) * N + n0 + tx];
    __syncthreads();
    const int kg = k0 >> 5;
    #pragma unroll
    for (int i = 0; i < 32; i += 8) {
        const float v = tile[tx][ty + i];
        const bf16 hi = f2b(v);
        const bf16 lo = f2b(v - b2f(hi));
        bf16* o = out + (size_t)(n0 + ty + i) * 8192 + kg * 64 + tx;
        o[0] = hi; o[32] = lo;
    }
}

__global__ void cnorm_kernel(const float* __restrict__ cb, float* __restrict__ cnorm)
{
    const int i = blockIdx.x * blockDim.x + threadIdx.x;
    if (i < 768) {
        float s = 0.f;
        for (int k = 0; k < 32; ++k) { const float v = cb[i * 32 + k]; s += v * v; }
        cnorm[i] = s;
    }
}

// ---------------------------------------------------------------------------
// Fused VQ projection weights: Wfuse[n=e*32+c][d2] = sum_h Wd3[d2][h]*Win[e][h][c]
// emitted split3 (hi,lo,hi) as B-side for gemm_bt; rows 96..127 zero.
// ---------------------------------------------------------------------------
__global__ __launch_bounds__(256)
void wfuse_kernel(const float* __restrict__ Wd3, const float* __restrict__ bd3,
                  const float* __restrict__ Win, const float* __restrict__ bin_,
                  bf16* __restrict__ BtS, float* __restrict__ bfuse)
{
    const int n = blockIdx.x;       // 0..127
    const int t = threadIdx.x;      // 0..255 == d2
    if (n >= 96) {
        bf16* o = BtS + (size_t)n * 768 + 3 * t;
        o[0] = f2b(0.f); o[1] = f2b(0.f); o[2] = f2b(0.f);
        if (t == 0) bfuse[n] = 0.f;
        return;
    }
    const int e = n >> 5, c = n & 31;
    float s = 0.f;
    for (int h = 0; h < 128; ++h)
        s += Wd3[t * 128 + h] * Win[(size_t)(e * 128 + h) * 32 + c];
    const bf16 hi = f2b(s);
    const bf16 lo = f2b(s - b2f(hi));
    bf16* o = BtS + (size_t)n * 768 + 3 * t;
    o[0] = hi; o[1] = lo; o[2] = hi;
    if (t == 0) {
        float b = bin_[e * 32 + c];
        for (int h = 0; h < 128; ++h)
            b += bd3[h] * Win[(size_t)(e * 128 + h) * 32 + c];
        bfuse[n] = b;
    }
}

// ---------------------------------------------------------------------------
// Layer-1 GEMM with on-the-fly hi/lo split of A = x (f32).
// As/Bs [128 rows][64 slots] bf16 (hi 0-31 | lo 32-63), XOR-swizzled 16B
// chunks; 32 KB LDS -> 4 blocks/CU, grid 1024 = fully resident.
// v6: (a) A-colocated XCD remap: 2 XCDs per kz; within an XCD the 4 n0-blocks
// sharing each x-chunk are colocated (n0 fastest) -> x fetched once per L2;
// the XCD's whole B kz-slice (2.1 MB) is L2-resident.
// (b) register A(ks+1) prefetch issued before the pack; the __syncthreads
// vmcnt drain (already paid for B) covers it, so pack never waits on HBM.
// Both barriers remain __syncthreads (no hand-rolled sync).
// ---------------------------------------------------------------------------
__global__ __launch_bounds__(256, 4)
void gemm1_x3(const float* __restrict__ A, const bf16* __restrict__ Bhl,
              float* __restrict__ part)
{
    __shared__ bf16 As[128 * 64];
    __shared__ bf16 Bs[128 * 64];
    const int t = threadIdx.x, lane = t & 63, w = t >> 6;
    // A-colocated XCD remap (hw dispatch: consecutive linear ids round-robin XCDs)
    const int bid = blockIdx.x + blockIdx.y * 4 + blockIdx.z * 256;  // 0..1023
    const int xcd = bid & 7;               // 0..7
    const int r   = bid >> 3;              // 0..127 within XCD
    const int kz  = xcd >> 1;              // 2 XCDs per K-chunk
    const int m0  = ((xcd & 1) * 32 + (r >> 2)) * 128;
    const int n0  = (r & 3) * 128;
    const int wr = w >> 1, wc = w & 1, l15 = lane & 15, quad = lane >> 4;
    const int offh = ((quad ^ (l15 & 7)) << 3);
    const int offl = offh ^ 32;

    f32x4 acc[4][4];
    #pragma unroll
    for (int i = 0; i < 4; ++i)
        #pragma unroll
        for (int jj = 0; jj < 4; ++jj)
            #pragma unroll
            for (int rr = 0; rr < 4; ++rr) acc[i][jj][rr] = 0.f;

    // A-pack mapping: row = t>>1, half = t&1 (16 consecutive f32 each)
    const int arow = t >> 1, ahalf = t & 1, arx = arow & 7;
    bf16* const aw0 = As + arow * 64 + (((ahalf * 2 + 0) ^ arx) << 3);        // hi chunk
    bf16* const aw1 = As + arow * 64 + (((ahalf * 2 + 1) ^ arx) << 3);        // hi chunk
    bf16* const aw2 = As + arow * 64 + (((4 + ahalf * 2 + 0) ^ arx) << 3);    // lo chunk
    bf16* const aw3 = As + arow * 64 + (((4 + ahalf * 2 + 1) ^ arx) << 3);    // lo chunk

    // B loader: physical chunk p -> row = p>>3, logical chunk = (p&7)^(row&7)
    int brow[4], bco[4];
    #pragma unroll
    for (int i = 0; i < 4; ++i) {
        const int p = i * 256 + t;
        brow[i] = p >> 3;
        bco[i] = ((p & 7) ^ (brow[i] & 7)) * 8;
    }

    const int s0 = kz * 32, s1 = s0 + 32;
    const float* const apbase = A + (size_t)(m0 + arow) * 4096 + ahalf * 16;

    // prologue: A(s0) -> f
    float f[16];
    {
        const float* ap = apbase + s0 * 32;
        *(float4*)(f + 0)  = *(const float4*)(ap + 0);
        *(float4*)(f + 4)  = *(const float4*)(ap + 4);
        *(float4*)(f + 8)  = *(const float4*)(ap + 8);
        *(float4*)(f + 12) = *(const float4*)(ap + 12);
    }

    for (int ks = s0; ks < s1; ++ks) {
        const bool haveNext = (ks + 1 < s1);
        // issue B(ks) global->LDS (async, drains at barrier-1)
        #pragma unroll
        for (int i = 0; i < 4; ++i) {
            const bf16* gb = Bhl + (size_t)(n0 + brow[i]) * 8192 + ks * 64 + bco[i];
            __builtin_amdgcn_global_load_lds(
                (const __attribute__((address_space(1))) void*)gb,
                (__attribute__((address_space(3))) void*)(Bs + (size_t)(i * 256 + t) * 8), 16, 0, 0);
        }
        // issue A(ks+1) register prefetch (completes by barrier-1's drain)
        float g[16];
        if (haveNext) {
            const float* ap = apbase + (ks + 1) * 32;
            *(float4*)(g + 0)  = *(const float4*)(ap + 0);
            *(float4*)(g + 4)  = *(const float4*)(ap + 4);
            *(float4*)(g + 8)  = *(const float4*)(ap + 8);
            *(float4*)(g + 12) = *(const float4*)(ap + 12);
        }
        // split + pack A(ks) (data already resident in f)
        {
            u32x4 hv, lv;
            #pragma unroll
            for (int jj = 0; jj < 4; ++jj) {
                const bf16 h0 = f2b(f[2 * jj]), h1 = f2b(f[2 * jj + 1]);
                const u32 l0 = bits(f2b(f[2 * jj] - b2f(h0)));
                const u32 l1 = bits(f2b(f[2 * jj + 1] - b2f(h1)));
                hv[jj] = (u32)bits(h0) | ((u32)bits(h1) << 16);
                lv[jj] = l0 | (l1 << 16);
            }
            *(u32x4*)aw0 = hv; *(u32x4*)aw2 = lv;
            #pragma unroll
            for (int jj = 0; jj < 4; ++jj) {
                const bf16 h0 = f2b(f[8 + 2 * jj]), h1 = f2b(f[8 + 2 * jj + 1]);
                const u32 l0 = bits(f2b(f[8 + 2 * jj] - b2f(h0)));
                const u32 l1 = bits(f2b(f[8 + 2 * jj + 1] - b2f(h1)));
                hv[jj] = (u32)bits(h0) | ((u32)bits(h1) << 16);
                lv[jj] = l0 | (l1 << 16);
            }
            *(u32x4*)aw1 = hv; *(u32x4*)aw3 = lv;
        }
        __syncthreads();
        {
            bf16x8 ah[4], al[4];
            #pragma unroll
            for (int mi = 0; mi < 4; ++mi) {
                const bf16* ar = As + (wr * 64 + mi * 16 + l15) * 64;
                ah[mi] = *(const bf16x8*)(ar + offh);
                al[mi] = *(const bf16x8*)(ar + offl);
            }
            #pragma unroll
            for (int ni = 0; ni < 4; ++ni) {
                const bf16* br = Bs + (wc * 64 + ni * 16 + l15) * 64;
                const bf16x8 bh = *(const bf16x8*)(br + offh);
                const bf16x8 bl = *(const bf16x8*)(br + offl);
                #pragma unroll
                for (int mi = 0; mi < 4; ++mi) {
                    acc[mi][ni] = __builtin_amdgcn_mfma_f32_16x16x32_bf16(ah[mi], bh, acc[mi][ni], 0, 0, 0);
                    acc[mi][ni] = __builtin_amdgcn_mfma_f32_16x16x32_bf16(al[mi], bh, acc[mi][ni], 0, 0, 0);
                    acc[mi][ni] = __builtin_amdgcn_mfma_f32_16x16x32_bf16(ah[mi], bl, acc[mi][ni], 0, 0, 0);
                }
            }
        }
        __syncthreads();
        if (haveNext) {
            #pragma unroll
            for (int k = 0; k < 16; ++k) f[k] = g[k];
        }
    }

    float* op = part + (size_t)kz * (8192ull * 512);
    #pragma unroll
    for (int mi = 0; mi < 4; ++mi)
        #pragma unroll
        for (int ni = 0; ni < 4; ++ni) {
            const int col = n0 + wc * 64 + ni * 16 + l15;
            #pragma unroll
            for (int rr = 0; rr < 4; ++rr) {
                const int row = m0 + wr * 64 + mi * 16 + quad * 4 + rr;
                op[(size_t)row * 512 + col] = acc[mi][ni][rr];
            }
        }
}

// ---------------------------------------------------------------------------
// Layer-1 epilogue: sum 4 K-split partials + bias, ReLU, emit split3 (hi,hi,lo).
// ---------------------------------------------------------------------------
__global__ __launch_bounds__(256)
void h1_epi(const float* __restrict__ part, const float* __restrict__ bias,
            bf16* __restrict__ out)
{
    const int idx = blockIdx.x * 256 + threadIdx.x;   // 0 .. 8192*128-1
    const int r = idx >> 7, c4 = idx & 127;
    const size_t base = (size_t)r * 512 + c4 * 4;
    const float4 p0 = *(const float4*)(part + 0ull * 8192 * 512 + base);
    const float4 p1 = *(const float4*)(part + 1ull * 8192 * 512 + base);
    const float4 p2 = *(const float4*)(part + 2ull * 8192 * 512 + base);
    const float4 p3 = *(const float4*)(part + 3ull * 8192 * 512 + base);
    const float4 bv = *(const float4*)(bias + c4 * 4);
    float v[4];
    v[0] = p0.x + p1.x + p2.x + p3.x + bv.x;
    v[1] = p0.y + p1.y + p2.y + p3.y + bv.y;
    v[2] = p0.z + p1.z + p2.z + p3.z + bv.z;
    v[3] = p0.w + p1.w + p2.w + p3.w + bv.w;
    u64 h[4], l[4];
    #pragma unroll
    for (int j = 0; j < 4; ++j) {
        const float vv = v[j] > 0.f ? v[j] : 0.f;
        const bf16 hi = f2b(vv);
        h[j] = bits(hi);
        l[j] = bits(f2b(vv - b2f(hi)));
    }
    const u64 w0 = h[0] | (h[0] << 16) | (l[0] << 32) | (h[1] << 48);
    const u64 w1 = h[1] | (l[1] << 16) | (h[2] << 32) | (h[2] << 48);
    const u64 w2 = l[2] | (h[3] << 16) | (h[3] << 32) | (l[3] << 48);
    u64* dst = (u64*)(out + (size_t)r * 1536 + 12 * c4);
    dst[0] = w0; dst[1] = w1; dst[2] = w2;
}

// ---------------------------------------------------------------------------
// Generic bf16 MFMA GEMM. EPI: 0 = f32 out; 1 = split3 bf16 (hi,hi,lo, ldc=3N);
// 2 = bf16 out; 3 = f32 out with clip[-1,1].  Grid: (N/128, M/128).
// ---------------------------------------------------------------------------
template <int EPI, int RELU>
__global__ __launch_bounds__(256)
void gemm_bt(const bf16* __restrict__ A, const bf16* __restrict__ Bt,
             const float* __restrict__ bias, void* __restrict__ outp,
             int M, int N, int K)
{
    __shared__ bf16 As[128 * 64];
    __shared__ bf16 Bs[128 * 64];
    const int t = threadIdx.x, lane = t & 63, w = t >> 6;
    const int n0 = blockIdx.x * 128;
    const int m0 = blockIdx.y * 128;
    const int wr = w >> 1, wc = w & 1, l15 = lane & 15, quad = lane >> 4;
    const int l7 = l15 & 7;

    f32x4 acc[4][4];
    #pragma unroll
    for (int i = 0; i < 4; ++i)
        #pragma unroll
        for (int j = 0; j < 4; ++j)
            #pragma unroll
            for (int r = 0; r < 4; ++r) acc[i][j][r] = 0.f;

    // loader: physical chunk c -> row = c>>3, sub = (c&7) ^ (row&7)
    int lrow[4], lcol[4];
    #pragma unroll
    for (int i = 0; i < 4; ++i) {
        const int c = i * 256 + t;
        lrow[i] = c >> 3;
        lcol[i] = ((c & 7) ^ (lrow[i] & 7)) * 8;
    }

    for (int k0 = 0; k0 < K; k0 += 64) {
        #pragma unroll
        for (int i = 0; i < 4; ++i) {
            const int c = i * 256 + t;
            const bf16* ga = A  + (size_t)(m0 + lrow[i]) * K + k0 + lcol[i];
            const bf16* gb = Bt + (size_t)(n0 + lrow[i]) * K + k0 + lcol[i];
            __builtin_amdgcn_global_load_lds(
                (const __attribute__((address_space(1))) void*)ga,
                (__attribute__((address_space(3))) void*)(As + (size_t)c * 8), 16, 0, 0);
            __builtin_amdgcn_global_load_lds(
                (const __attribute__((address_space(1))) void*)gb,
                (__attribute__((address_space(3))) void*)(Bs + (size_t)c * 8), 16, 0, 0);
        }
        __syncthreads();
        #pragma unroll
        for (int kk = 0; kk < 2; ++kk) {
            const int sw = (((kk << 2) | quad) ^ l7) << 3;
            bf16x8 af[4], bfr[4];
            #pragma unroll
            for (int mi = 0; mi < 4; ++mi)
                af[mi] = *(const bf16x8*)(As + (wr * 64 + mi * 16 + l15) * 64 + sw);
            #pragma unroll
            for (int ni = 0; ni < 4; ++ni)
                bfr[ni] = *(const bf16x8*)(Bs + (wc * 64 + ni * 16 + l15) * 64 + sw);
            #pragma unroll
            for (int mi = 0; mi < 4; ++mi)
                #pragma unroll
                for (int ni = 0; ni < 4; ++ni)
                    acc[mi][ni] = __builtin_amdgcn_mfma_f32_16x16x32_bf16(
                        af[mi], bfr[ni], acc[mi][ni], 0, 0, 0);
        }
        __syncthreads();
    }

    #pragma unroll
    for (int mi = 0; mi < 4; ++mi)
        #pragma unroll
        for (int ni = 0; ni < 4; ++ni) {
            const int col = n0 + wc * 64 + ni * 16 + l15;
            const float bv = bias[col];
            #pragma unroll
            for (int r = 0; r < 4; ++r) {
                const int row = m0 + wr * 64 + mi * 16 + quad * 4 + r;
                float v = acc[mi][ni][r] + bv;
                if (RELU) v = v > 0.f ? v : 0.f;
                if (EPI == 0) {
                    ((float*)outp)[(size_t)row * N + col] = v;
                } else if (EPI == 1) {
                    const bf16 hi = f2b(v);
                    const bf16 lo = f2b(v - b2f(hi));
                    bf16* o = (bf16*)outp + (size_t)row * 3 * N + 3 * col;
                    o[0] = hi; o[1] = hi; o[2] = lo;
                } else if (EPI == 2) {
                    ((bf16*)outp)[(size_t)row * N + col] = f2b(v);
                } else {
                    v = fminf(fmaxf(v, -1.f), 1.f);
                    ((float*)outp)[(size_t)row * N + col] = v;
                }
            }
        }
}

// ---------------------------------------------------------------------------
// VQ stage 2: one block per (expert, 32-row chunk). Grid 768 (3 x 256).
// ---------------------------------------------------------------------------
__global__ __launch_bounds__(256)
void vq2_kernel(const float* __restrict__ xe_buf, const float* __restrict__ cb,
                const float* __restrict__ cnorm, const float* __restrict__ Wout,
                const float* __restrict__ bout, float* __restrict__ qemb,
                float* __restrict__ idx_out, float* __restrict__ commit_acc)
{
    __shared__ float cb_s[256 * 36];   // padded: row stride 36 (16B-aligned, uniform banks)
    __shared__ float wo_s[32 * 128];
    __shared__ float cn_s[256];
    __shared__ float bo_s[128];
    __shared__ float xe_s[4 * 32];
    __shared__ float q_s[4 * 32];
    __shared__ int   idx_s[4];
    __shared__ u64   wred[4][4];
    __shared__ float cred[256];

    const int e  = blockIdx.x >> 8;        // 0..2
    const int rb = blockIdx.x & 255;       // 0..255 (32-row chunks)
    const int t = threadIdx.x, lane = t & 63, w = t >> 6;

    for (int j = t; j < 256 * 32; j += 256) {
        const int code = j >> 5, c = j & 31;
        cb_s[code * 36 + c] = cb[(size_t)e * 8192 + j];
    }
    for (int j = t; j < 4096; j += 256) wo_s[j] = Wout[(size_t)e * 4096 + j];
    cn_s[t] = cnorm[e * 256 + t];
    if (t < 128) bo_s[t] = bout[e * 128 + t];
    float commit_loc = 0.f;
    __syncthreads();

    for (int it = 0; it < 8; ++it) {
        const int r0 = rb * 32 + it * 4;
        if (t < 128) {
            const int r4 = t >> 5, c = t & 31;
            xe_s[r4 * 32 + c] = xe_buf[(size_t)(r0 + r4) * 128 + e * 32 + c];
        }
        __syncthreads();

        u64 key[4];
        {
            const float4* cp = (const float4*)(cb_s + t * 36);
            const float cn = cn_s[t];
            #pragma unroll
            for (int r4 = 0; r4 < 4; ++r4) {
                float dot = 0.f;
                #pragma unroll
                for (int c4 = 0; c4 < 8; ++c4) {
                    const float4 cv = cp[c4];
                    const float4 xv = *(const float4*)(xe_s + r4 * 32 + c4 * 4);
                    dot += xv.x * cv.x + xv.y * cv.y + xv.z * cv.z + xv.w * cv.w;
                }
                const float d = cn - 2.f * dot;
                u32 ub = __builtin_bit_cast(u32, d);
                ub = (ub & 0x80000000u) ? ~ub : (ub | 0x80000000u);
                key[r4] = ((u64)ub << 32) | (u32)t;
            }
        }
        #pragma unroll
        for (int off = 32; off; off >>= 1) {
            #pragma unroll
            for (int r4 = 0; r4 < 4; ++r4) {
                const u64 o = __shfl_down(key[r4], off, 64);
                if (o < key[r4]) key[r4] = o;
            }
        }
        if (lane == 0) {
            #pragma unroll
            for (int r4 = 0; r4 < 4; ++r4) wred[r4][w] = key[r4];
        }
        __syncthreads();
        if (t < 4) {
            u64 k = wred[t][0];
            #pragma unroll
            for (int ww = 1; ww < 4; ++ww) if (wred[t][ww] < k) k = wred[t][ww];
            const int code = (int)(k & 0xFFFFFFFFu);
            idx_s[t] = code;
            idx_out[(size_t)(r0 + t) * 3 + e] = (float)code;
        }
        __syncthreads();
        if (t < 128) {
            const int r4 = t >> 5, c = t & 31;
            const float q = cb_s[idx_s[r4] * 36 + c];
            q_s[r4 * 32 + c] = q;
            const float dd = q - xe_s[r4 * 32 + c];
            commit_loc += dd * dd;
        }
        __syncthreads();
        #pragma unroll
        for (int p = 0; p < 2; ++p) {
            const int j = p * 256 + t;
            const int r4 = j >> 7, h = j & 127;
            float s = bo_s[h];
            #pragma unroll
            for (int c = 0; c < 32; ++c) s += q_s[r4 * 32 + c] * wo_s[c * 128 + h];
            qemb[((size_t)e * 8192 + r0 + r4) * 128 + h] = s;
        }
        __syncthreads();
    }

    cred[t] = commit_loc;
    __syncthreads();
    for (int o = 128; o; o >>= 1) { if (t < o) cred[t] += cred[t + o]; __syncthreads(); }
    if (t == 0) atomicAdd(commit_acc, cred[0]);
}

// ---------------------------------------------------------------------------
// rl = mean_e qemb (bf16) + per-h expert sums for the decorrelation mean.
// ---------------------------------------------------------------------------
__global__ __launch_bounds__(256)
void rlmean_kernel(const float* __restrict__ qemb, bf16* __restrict__ rl,
                   float* __restrict__ meanAcc)
{
    const int t = threadIdx.x, h = t & 127, half = t >> 7;
    const int r0 = blockIdx.x * 64;
    float a0 = 0.f, a1 = 0.f, a2 = 0.f;
    for (int r = r0 + half; r < r0 + 64; r += 2) {
        const float v0 = qemb[((size_t)0 * 8192 + r) * 128 + h];
        const float v1 = qemb[((size_t)1 * 8192 + r) * 128 + h];
        const float v2 = qemb[((size_t)2 * 8192 + r) * 128 + h];
        a0 += v0; a1 += v1; a2 += v2;
        rl[(size_t)r * 128 + h] = f2b((v0 + v1 + v2) * (1.f / 3.f));
    }
    __shared__ float red[3][256];
    red[0][t] = a0; red[1][t] = a1; red[2][t] = a2;
    __syncthreads();
    if (t < 128) {
        atomicAdd(&meanAcc[0 * 128 + h], red[0][t] + red[0][t + 128]);
        atomicAdd(&meanAcc[1 * 128 + h], red[1][t] + red[1][t + 128]);
        atomicAdd(&meanAcc[2 * 128 + h], red[2][t] + red[2][t + 128]);
    }
}

__global__ __launch_bounds__(256)
void gram_kernel(const float* __restrict__ qemb, const float* __restrict__ meanAcc,
                 double* __restrict__ gram)
{
    const int t = threadIdx.x;
    const int h = t & 127, half = t >> 7;
    const int b0 = blockIdx.x * 32;
    const float m0 = meanAcc[0 * 128 + h] * (1.f / 8192.f);
    const float m1 = meanAcc[1 * 128 + h] * (1.f / 8192.f);
    const float m2 = meanAcc[2 * 128 + h] * (1.f / 8192.f);
    float g[6] = {0, 0, 0, 0, 0, 0};
    for (int b = b0 + half; b < b0 + 32; b += 2) {
        const float v0 = qemb[((size_t)0 * 8192 + b) * 128 + h] - m0;
        const float v1 = qemb[((size_t)1 * 8192 + b) * 128 + h] - m1;
        const float v2 = qemb[((size_t)2 * 8192 + b) * 128 + h] - m2;
        g[0] += v0 * v0; g[1] += v0 * v1; g[2] += v0 * v2;
        g[3] += v1 * v1; g[4] += v1 * v2; g[5] += v2 * v2;
    }
    __shared__ float red[256];
    for (int i = 0; i < 6; ++i) {
        red[t] = g[i];
        __syncthreads();
        for (int o = 128; o; o >>= 1) { if (t < o) red[t] += red[t + o]; __syncthreads(); }
        if (t == 0) atomicAdd(&gram[i], (double)red[0]);
        __syncthreads();
    }
}

__global__ void final_kernel(const float* __restrict__ commit_acc,
                             const double* __restrict__ gram,
                             float* __restrict__ out2)
{
    if (threadIdx.x != 0 || blockIdx.x != 0) return;
    const double denom = 8192.0 * 128.0 - 1.0;
    const double c00 = gram[0] / denom, c01 = gram[1] / denom, c02 = gram[2] / denom;
    const double c11 = gram[3] / denom, c12 = gram[4] / denom, c22 = gram[5] / denom;
    double s0 = sqrt(c00), s1 = sqrt(c11), s2 = sqrt(c22);
    if (!(s0 > 1e-8)) s0 = 1.0;
    if (!(s1 > 1e-8)) s1 = 1.0;
    if (!(s2 > 1e-8)) s2 = 1.0;
    const double r01 = c01 / (s0 * s1), r02 = c02 / (s0 * s2), r12 = c12 / (s1 * s2);
    const double decorr = 2.0 * (r01 * r01 + r02 * r02 + r12 * r12);
    out2[0] = (float)((double)commit_acc[0] * (0.25 / (8192.0 * 32.0)));
    out2[1] = (float)decorr;
}

// ---------------------------------------------------------------------------
extern "C" void kernel_launch(void* const* d_in, const int* in_sizes, int n_in,
                              void* d_out, int out_size, void* d_ws, size_t ws_size,
                              hipStream_t stream)
{
    const float* x    = (const float*)d_in[0];
    const float* Wd1  = (const float*)d_in[1];
    const float* bd1  = (const float*)d_in[2];
    const float* Wd2  = (const float*)d_in[3];
    const float* bd2  = (const float*)d_in[4];
    const float* Wd3  = (const float*)d_in[5];
    const float* bd3  = (const float*)d_in[6];
    const float* Win  = (const float*)d_in[7];
    const float* bin_ = (const float*)d_in[8];
    const float* cb   = (const float*)d_in[9];
    const float* Wout = (const float*)d_in[10];
    const float* bout = (const float*)d_in[11];
    const float* Wu1  = (const float*)d_in[12];
    const float* bu1  = (const float*)d_in[13];
    const float* Wu2  = (const float*)d_in[14];
    const float* bu2  = (const float*)d_in[15];
    const float* Wu3  = (const float*)d_in[16];
    const float* bu3  = (const float*)d_in[17];

    char* ws = (char*)d_ws;
    bf16*  Wd1s   = (bf16*)(ws + OFF_WD1S);
    bf16*  Wd2s   = (bf16*)(ws + OFF_WD2S);
    bf16*  WfuseS = (bf16*)(ws + OFF_WFUS);
    bf16*  Wu1T   = (bf16*)(ws + OFF_WU1T);
    bf16*  Wu2T   = (bf16*)(ws + OFF_WU2T);
    bf16*  Wu3T   = (bf16*)(ws + OFF_WU3T);
    bf16*  h1s    = (bf16*)(ws + OFF_H1S);
    bf16*  h2s    = (bf16*)(ws + OFF_H2S);
    float* xe     = (float*)(ws + OFF_XE);
    float* qemb   = (float*)(ws + OFF_QEMB);
    bf16*  rl     = (bf16*)(ws + OFF_RL);
    bf16*  u1     = (bf16*)(ws + OFF_U1);
    bf16*  u2     = (bf16*)(ws + OFF_U2);
    float* cnorm  = (float*)(ws + OFF_CNRM);
    float* bfuse  = (float*)(ws + OFF_BFUS);
    float* commit = (float*)(ws + OFF_STAT);
    double* gram  = (double*)(ws + OFF_STAT + 8);
    float* meanA  = (float*)(ws + OFF_STAT + 64);
    float* part   = (float*)(ws + OFF_PART);

    float* out_f   = (float*)d_out;
    float* idx_out = out_f + (size_t)8192 * 4096;
    float* scal    = idx_out + (size_t)8192 * 3;

    hipMemsetAsync(ws + OFF_STAT, 0, 2048, stream);

    const dim3 tb(32, 8);
    wtrans_hilo<<<dim3(16, 128), tb, 0, stream>>>(Wd1, Wd1s, 4096, 512);
    wtrans_split3<<<dim3(8, 16),   tb, 0, stream>>>(Wd2, Wd2s, 512, 256);
    wtrans_bf16<<<dim3(8, 4),      tb, 0, stream>>>(Wu1, Wu1T, 128, 256);
    wtrans_bf16<<<dim3(16, 8),     tb, 0, stream>>>(Wu2, Wu2T, 256, 512);
    wtrans_bf16<<<dim3(128, 16),   tb, 0, stream>>>(Wu3, Wu3T, 512, 4096);
    cnorm_kernel<<<3, 256, 0, stream>>>(cb, cnorm);
    wfuse_kernel<<<128, 256, 0, stream>>>(Wd3, bd3, Win, bin_, WfuseS, bfuse);

    // down MLP (split bf16, ~f32 accuracy) ending directly in xe = latent@Win+...
    gemm1_x3<<<dim3(4, 64, 4), 256, 0, stream>>>(x, Wd1s, part);
    h1_epi<<<4096, 256, 0, stream>>>(part, bd1, h1s);
    gemm_bt<1, 1><<<dim3(2, 64), 256, 0, stream>>>(h1s, Wd2s, bd2, h2s, 8192, 256, 1536);
    gemm_bt<0, 0><<<dim3(1, 64), 256, 0, stream>>>(h2s, WfuseS, bfuse, xe, 8192, 128, 768);

    vq2_kernel<<<768, 256, 0, stream>>>(xe, cb, cnorm, Wout, bout, qemb, idx_out, commit);
    rlmean_kernel<<<128, 256, 0, stream>>>(qemb, rl, meanA);
    gram_kernel<<<256, 256, 0, stream>>>(qemb, meanA, gram);
    final_kernel<<<1, 64, 0, stream>>>(commit, gram, scal);

    // up MLP: plain bf16 compute, f32 recon out
    gemm_bt<2, 1><<<dim3(2, 64),  256, 0, stream>>>(rl, Wu1T, bu1, u1,    8192, 256,  128);
    gemm_bt<2, 1><<<dim3(4, 64),  256, 0, stream>>>(u1, Wu2T, bu2, u2,    8192, 512,  256);
    gemm_bt<3, 0><<<dim3(32, 64), 256, 0, stream>>>(u2, Wu3T, bu3, out_f, 8192, 4096, 512);

    (void)in_sizes; (void)n_in; (void)out_size; (void)ws_size;
}

// Round 7
// 654.726 us; speedup vs baseline: 1.6641x; 1.6641x over previous
//
#include <hip/hip_runtime.h>
#include <hip/hip_bf16.h>

using bf16 = __hip_bfloat16;

typedef __bf16 bf16x8 __attribute__((ext_vector_type(8)));
typedef float  f32x4  __attribute__((ext_vector_type(4)));
typedef unsigned int u32x4 __attribute__((ext_vector_type(4)));
typedef unsigned long long u64;
typedef unsigned short u16;
typedef unsigned int u32;

__device__ __forceinline__ float b2f(bf16 v) { return __bfloat162float(v); }
__device__ __forceinline__ bf16  f2b(float v) { return __float2bfloat16(v); }
__device__ __forceinline__ u16   bits(bf16 v) { return __builtin_bit_cast(u16, v); }

// ---------------------------------------------------------------------------
// Workspace layout
// ---------------------------------------------------------------------------
static constexpr size_t SZ_WD1S = 512ull  * 8192  * 2;  // bf16 [512][128 kg][hi32|lo32]
static constexpr size_t SZ_WD2S = 256ull  * 1536  * 2;  // bf16 [256][3*512] split3
static constexpr size_t SZ_WFUS = 128ull  * 768   * 2;  // bf16 [128][3*256] (Wd3@Win fused, split3)
static constexpr size_t SZ_WU1T = 256ull  * 128   * 2;
static constexpr size_t SZ_WU2T = 512ull  * 256   * 2;
static constexpr size_t SZ_WU3T = 4096ull * 512   * 2;
static constexpr size_t SZ_H1S  = 8192ull * 1536  * 2;  // bf16 [8192][3*512] (hi,hi,lo)
static constexpr size_t SZ_H2S  = 8192ull * 768   * 2;  // bf16 [8192][3*256]
static constexpr size_t SZ_XE   = 8192ull * 128   * 4;  // f32 xe (cols e*32+c, 96..127 unused)
static constexpr size_t SZ_QEMB = 3ull * 8192 * 128 * 4;// f32
static constexpr size_t SZ_RL   = 8192ull * 128   * 2;  // bf16
static constexpr size_t SZ_U1   = 8192ull * 256   * 2;
static constexpr size_t SZ_U2   = 8192ull * 512   * 2;
static constexpr size_t SZ_CNRM = 768ull * 4;
static constexpr size_t SZ_BFUS = 128ull * 4;
static constexpr size_t SZ_PART = 4ull * 8192 * 512 * 4; // f32 K-split partials (4 slabs)

static constexpr size_t OFF_WD1S = 0;
static constexpr size_t OFF_WD2S = OFF_WD1S + SZ_WD1S;
static constexpr size_t OFF_WFUS = OFF_WD2S + SZ_WD2S;
static constexpr size_t OFF_WU1T = OFF_WFUS + SZ_WFUS;
static constexpr size_t OFF_WU2T = OFF_WU1T + SZ_WU1T;
static constexpr size_t OFF_WU3T = OFF_WU2T + SZ_WU2T;
static constexpr size_t OFF_H1S  = OFF_WU3T + SZ_WU3T;
static constexpr size_t OFF_H2S  = OFF_H1S  + SZ_H1S;
static constexpr size_t OFF_XE   = OFF_H2S  + SZ_H2S;
static constexpr size_t OFF_QEMB = OFF_XE   + SZ_XE;
static constexpr size_t OFF_RL   = OFF_QEMB + SZ_QEMB;
static constexpr size_t OFF_U1   = OFF_RL   + SZ_RL;
static constexpr size_t OFF_U2   = OFF_U1   + SZ_U1;
static constexpr size_t OFF_CNRM = OFF_U2   + SZ_U2;
static constexpr size_t OFF_BFUS = OFF_CNRM + ((SZ_CNRM + 255) & ~size_t(255));
static constexpr size_t OFF_STAT = OFF_BFUS + ((SZ_BFUS + 255) & ~size_t(255));
// stats (memset 0 each launch): +0 f32 commit; +8 double gram[6]; +64 f32 meanAcc[384]
static constexpr size_t OFF_PART = OFF_STAT + 2048;

// ---------------------------------------------------------------------------
// Weight transposes: in [K][N] f32.
// ---------------------------------------------------------------------------
__global__ void wtrans_bf16(const float* __restrict__ in, bf16* __restrict__ out,
                            int K, int N)
{
    __shared__ float tile[32][33];
    const int tx = threadIdx.x, ty = threadIdx.y;
    const int n0 = blockIdx.x * 32, k0 = blockIdx.y * 32;
    #pragma unroll
    for (int i = 0; i < 32; i += 8)
        tile[ty + i][tx] = in[(size_t)(k0 + ty + i) * N + n0 + tx];
    __syncthreads();
    #pragma unroll
    for (int i = 0; i < 32; i += 8)
        out[(size_t)(n0 + ty + i) * K + k0 + tx] = f2b(tile[tx][ty + i]);
}

__global__ void wtrans_split3(const float* __restrict__ in, bf16* __restrict__ out,
                              int K, int N)
{
    __shared__ float tile[32][33];
    const int tx = threadIdx.x, ty = threadIdx.y;
    const int n0 = blockIdx.x * 32, k0 = blockIdx.y * 32;
    #pragma unroll
    for (int i = 0; i < 32; i += 8)
        tile[ty + i][tx] = in[(size_t)(k0 + ty + i) * N + n0 + tx];
    __syncthreads();
    #pragma unroll
    for (int i = 0; i < 32; i += 8) {
        const float v = tile[tx][ty + i];
        const bf16 hi = f2b(v);
        const bf16 lo = f2b(v - b2f(hi));
        bf16* o = out + (size_t)(n0 + ty + i) * 3 * K + 3 * (k0 + tx);
        o[0] = hi; o[1] = lo; o[2] = hi;
    }
}

// Wd1 -> [n 0..511][kg 0..127][slot: hi k&31 | 32+ lo k&31]
__global__ void wtrans_hilo(const float* __restrict__ in, bf16* __restrict__ out,
                            int K, int N)
{
    __shared__ float tile[32][33];
    const int tx = threadIdx.x, ty = threadIdx.y;
    const int n0 = blockIdx.x * 32, k0 = blockIdx.y * 32;
    #pragma unroll
    for (int i = 0; i < 32; i += 8)
        tile[ty + i][tx] = in[(size_t)(k0 + ty + i) * N + n0 + tx];
    __syncthreads();
    const int kg = k0 >> 5;
    #pragma unroll
    for (int i = 0; i < 32; i += 8) {
        const float v = tile[tx][ty + i];
        const bf16 hi = f2b(v);
        const bf16 lo = f2b(v - b2f(hi));
        bf16* o = out + (size_t)(n0 + ty + i) * 8192 + kg * 64 + tx;
        o[0] = hi; o[32] = lo;
    }
}

__global__ void cnorm_kernel(const float* __restrict__ cb, float* __restrict__ cnorm)
{
    const int i = blockIdx.x * blockDim.x + threadIdx.x;
    if (i < 768) {
        float s = 0.f;
        for (int k = 0; k < 32; ++k) { const float v = cb[i * 32 + k]; s += v * v; }
        cnorm[i] = s;
    }
}

// ---------------------------------------------------------------------------
// Fused VQ projection weights: Wfuse[n=e*32+c][d2] = sum_h Wd3[d2][h]*Win[e][h][c]
// emitted split3 (hi,lo,hi) as B-side for gemm_bt; rows 96..127 zero.
// ---------------------------------------------------------------------------
__global__ __launch_bounds__(256)
void wfuse_kernel(const float* __restrict__ Wd3, const float* __restrict__ bd3,
                  const float* __restrict__ Win, const float* __restrict__ bin_,
                  bf16* __restrict__ BtS, float* __restrict__ bfuse)
{
    const int n = blockIdx.x;       // 0..127
    const int t = threadIdx.x;      // 0..255 == d2
    if (n >= 96) {
        bf16* o = BtS + (size_t)n * 768 + 3 * t;
        o[0] = f2b(0.f); o[1] = f2b(0.f); o[2] = f2b(0.f);
        if (t == 0) bfuse[n] = 0.f;
        return;
    }
    const int e = n >> 5, c = n & 31;
    float s = 0.f;
    for (int h = 0; h < 128; ++h)
        s += Wd3[t * 128 + h] * Win[(size_t)(e * 128 + h) * 32 + c];
    const bf16 hi = f2b(s);
    const bf16 lo = f2b(s - b2f(hi));
    bf16* o = BtS + (size_t)n * 768 + 3 * t;
    o[0] = hi; o[1] = lo; o[2] = hi;
    if (t == 0) {
        float b = bin_[e * 32 + c];
        for (int h = 0; h < 128; ++h)
            b += bd3[h] * Win[(size_t)(e * 128 + h) * 32 + c];
        bfuse[n] = b;
    }
}

// ---------------------------------------------------------------------------
// Layer-1 GEMM with on-the-fly hi/lo split of A = x (f32).
// As/Bs [128 rows][64 slots] bf16 (hi 0-31 | lo 32-63), XOR-swizzled 16B
// chunks; 32 KB LDS -> 4 blocks/CU, grid 1024 fully resident.
// v7: remap reverted to the v5 (measured-good) panel map; the v6 "A-colocated"
// map blew traffic up to 2.45 GB (FETCH 975 MB / WRITE 1.42 GB) — the
// block->XCD assumption doesn't hold strongly enough to colocate on.
// Keeps the safe register A(ks+1) prefetch: issue before the pack, plain
// __syncthreads both barriers (its drain completes the prefetch for free).
// ---------------------------------------------------------------------------
__global__ __launch_bounds__(256, 4)
void gemm1_x3(const float* __restrict__ A, const bf16* __restrict__ Bhl,
              float* __restrict__ part)
{
    __shared__ bf16 As[128 * 64];
    __shared__ bf16 Bs[128 * 64];
    const int t = threadIdx.x, lane = t & 63, w = t >> 6;
    // v5 XCD-panel remap (measured: 131 us, FETCH 267 MB)
    const int bid = blockIdx.x + blockIdx.y * 4 + blockIdx.z * 256;  // 0..1023
    const int xcd = bid & 7, j = bid >> 3;                           // 0..7, 0..127
    const int panel = xcd + 8 * (j >> 6);                            // 0..15
    const int n0 = (panel & 3) * 128;
    const int kz = panel >> 2;
    const int m0 = (j & 63) * 128;
    const int wr = w >> 1, wc = w & 1, l15 = lane & 15, quad = lane >> 4;
    const int offh = ((quad ^ (l15 & 7)) << 3);
    const int offl = offh ^ 32;

    f32x4 acc[4][4];
    #pragma unroll
    for (int i = 0; i < 4; ++i)
        #pragma unroll
        for (int jj = 0; jj < 4; ++jj)
            #pragma unroll
            for (int rr = 0; rr < 4; ++rr) acc[i][jj][rr] = 0.f;

    // A-pack mapping: row = t>>1, half = t&1 (16 consecutive f32 each)
    const int arow = t >> 1, ahalf = t & 1, arx = arow & 7;
    bf16* const aw0 = As + arow * 64 + (((ahalf * 2 + 0) ^ arx) << 3);        // hi chunk
    bf16* const aw1 = As + arow * 64 + (((ahalf * 2 + 1) ^ arx) << 3);        // hi chunk
    bf16* const aw2 = As + arow * 64 + (((4 + ahalf * 2 + 0) ^ arx) << 3);    // lo chunk
    bf16* const aw3 = As + arow * 64 + (((4 + ahalf * 2 + 1) ^ arx) << 3);    // lo chunk

    // B loader: physical chunk p -> row = p>>3, logical chunk = (p&7)^(row&7)
    int brow[4], bco[4];
    #pragma unroll
    for (int i = 0; i < 4; ++i) {
        const int p = i * 256 + t;
        brow[i] = p >> 3;
        bco[i] = ((p & 7) ^ (brow[i] & 7)) * 8;
    }

    const int s0 = kz * 32, s1 = s0 + 32;
    const float* const apbase = A + (size_t)(m0 + arow) * 4096 + ahalf * 16;

    // prologue: A(s0) -> f
    float f[16];
    {
        const float* ap = apbase + s0 * 32;
        *(float4*)(f + 0)  = *(const float4*)(ap + 0);
        *(float4*)(f + 4)  = *(const float4*)(ap + 4);
        *(float4*)(f + 8)  = *(const float4*)(ap + 8);
        *(float4*)(f + 12) = *(const float4*)(ap + 12);
    }

    for (int ks = s0; ks < s1; ++ks) {
        const bool haveNext = (ks + 1 < s1);
        // issue B(ks) global->LDS (async, drains at barrier-1)
        #pragma unroll
        for (int i = 0; i < 4; ++i) {
            const bf16* gb = Bhl + (size_t)(n0 + brow[i]) * 8192 + ks * 64 + bco[i];
            __builtin_amdgcn_global_load_lds(
                (const __attribute__((address_space(1))) void*)gb,
                (__attribute__((address_space(3))) void*)(Bs + (size_t)(i * 256 + t) * 8), 16, 0, 0);
        }
        // issue A(ks+1) register prefetch (completes by barrier-1's drain)
        float g[16];
        if (haveNext) {
            const float* ap = apbase + (ks + 1) * 32;
            *(float4*)(g + 0)  = *(const float4*)(ap + 0);
            *(float4*)(g + 4)  = *(const float4*)(ap + 4);
            *(float4*)(g + 8)  = *(const float4*)(ap + 8);
            *(float4*)(g + 12) = *(const float4*)(ap + 12);
        }
        // split + pack A(ks) (data already resident in f)
        {
            u32x4 hv, lv;
            #pragma unroll
            for (int jj = 0; jj < 4; ++jj) {
                const bf16 h0 = f2b(f[2 * jj]), h1 = f2b(f[2 * jj + 1]);
                const u32 l0 = bits(f2b(f[2 * jj] - b2f(h0)));
                const u32 l1 = bits(f2b(f[2 * jj + 1] - b2f(h1)));
                hv[jj] = (u32)bits(h0) | ((u32)bits(h1) << 16);
                lv[jj] = l0 | (l1 << 16);
            }
            *(u32x4*)aw0 = hv; *(u32x4*)aw2 = lv;
            #pragma unroll
            for (int jj = 0; jj < 4; ++jj) {
                const bf16 h0 = f2b(f[8 + 2 * jj]), h1 = f2b(f[8 + 2 * jj + 1]);
                const u32 l0 = bits(f2b(f[8 + 2 * jj] - b2f(h0)));
                const u32 l1 = bits(f2b(f[8 + 2 * jj + 1] - b2f(h1)));
                hv[jj] = (u32)bits(h0) | ((u32)bits(h1) << 16);
                lv[jj] = l0 | (l1 << 16);
            }
            *(u32x4*)aw1 = hv; *(u32x4*)aw3 = lv;
        }
        __syncthreads();
        {
            bf16x8 ah[4], al[4];
            #pragma unroll
            for (int mi = 0; mi < 4; ++mi) {
                const bf16* ar = As + (wr * 64 + mi * 16 + l15) * 64;
                ah[mi] = *(const bf16x8*)(ar + offh);
                al[mi] = *(const bf16x8*)(ar + offl);
            }
            #pragma unroll
            for (int ni = 0; ni < 4; ++ni) {
                const bf16* br = Bs + (wc * 64 + ni * 16 + l15) * 64;
                const bf16x8 bh = *(const bf16x8*)(br + offh);
                const bf16x8 bl = *(const bf16x8*)(br + offl);
                #pragma unroll
                for (int mi = 0; mi < 4; ++mi) {
                    acc[mi][ni] = __builtin_amdgcn_mfma_f32_16x16x32_bf16(ah[mi], bh, acc[mi][ni], 0, 0, 0);
                    acc[mi][ni] = __builtin_amdgcn_mfma_f32_16x16x32_bf16(al[mi], bh, acc[mi][ni], 0, 0, 0);
                    acc[mi][ni] = __builtin_amdgcn_mfma_f32_16x16x32_bf16(ah[mi], bl, acc[mi][ni], 0, 0, 0);
                }
            }
        }
        __syncthreads();
        if (haveNext) {
            #pragma unroll
            for (int k = 0; k < 16; ++k) f[k] = g[k];
        }
    }

    float* op = part + (size_t)kz * (8192ull * 512);
    #pragma unroll
    for (int mi = 0; mi < 4; ++mi)
        #pragma unroll
        for (int ni = 0; ni < 4; ++ni) {
            const int col = n0 + wc * 64 + ni * 16 + l15;
            #pragma unroll
            for (int rr = 0; rr < 4; ++rr) {
                const int row = m0 + wr * 64 + mi * 16 + quad * 4 + rr;
                op[(size_t)row * 512 + col] = acc[mi][ni][rr];
            }
        }
}

// ---------------------------------------------------------------------------
// Layer-1 epilogue: sum 4 K-split partials + bias, ReLU, emit split3 (hi,hi,lo).
// ---------------------------------------------------------------------------
__global__ __launch_bounds__(256)
void h1_epi(const float* __restrict__ part, const float* __restrict__ bias,
            bf16* __restrict__ out)
{
    const int idx = blockIdx.x * 256 + threadIdx.x;   // 0 .. 8192*128-1
    const int r = idx >> 7, c4 = idx & 127;
    const size_t base = (size_t)r * 512 + c4 * 4;
    const float4 p0 = *(const float4*)(part + 0ull * 8192 * 512 + base);
    const float4 p1 = *(const float4*)(part + 1ull * 8192 * 512 + base);
    const float4 p2 = *(const float4*)(part + 2ull * 8192 * 512 + base);
    const float4 p3 = *(const float4*)(part + 3ull * 8192 * 512 + base);
    const float4 bv = *(const float4*)(bias + c4 * 4);
    float v[4];
    v[0] = p0.x + p1.x + p2.x + p3.x + bv.x;
    v[1] = p0.y + p1.y + p2.y + p3.y + bv.y;
    v[2] = p0.z + p1.z + p2.z + p3.z + bv.z;
    v[3] = p0.w + p1.w + p2.w + p3.w + bv.w;
    u64 h[4], l[4];
    #pragma unroll
    for (int j = 0; j < 4; ++j) {
        const float vv = v[j] > 0.f ? v[j] : 0.f;
        const bf16 hi = f2b(vv);
        h[j] = bits(hi);
        l[j] = bits(f2b(vv - b2f(hi)));
    }
    const u64 w0 = h[0] | (h[0] << 16) | (l[0] << 32) | (h[1] << 48);
    const u64 w1 = h[1] | (l[1] << 16) | (h[2] << 32) | (h[2] << 48);
    const u64 w2 = l[2] | (h[3] << 16) | (h[3] << 32) | (l[3] << 48);
    u64* dst = (u64*)(out + (size_t)r * 1536 + 12 * c4);
    dst[0] = w0; dst[1] = w1; dst[2] = w2;
}

// ---------------------------------------------------------------------------
// Generic bf16 MFMA GEMM, tile BM x 128 (BM = 128 or 64).
// EPI: 0 = f32 out; 1 = split3 bf16 (hi,hi,lo, ldc=3N); 2 = bf16 out;
// 3 = f32 out with clip[-1,1].  Grid: (N/128, M/BM).
// BM=64 halves per-block work/LDS (24 KB -> ~6 blocks/CU) for narrow-N
// layers whose 128-tile grids underfill the GPU (64-256 blocks).
// ---------------------------------------------------------------------------
template <int EPI, int RELU, int BM>
__global__ __launch_bounds__(256)
void gemm_bt(const bf16* __restrict__ A, const bf16* __restrict__ Bt,
             const float* __restrict__ bias, void* __restrict__ outp,
             int M, int N, int K)
{
    constexpr int MI = BM / 32;            // m-fragments per wave
    __shared__ bf16 As[BM * 64];
    __shared__ bf16 Bs[128 * 64];
    const int t = threadIdx.x, lane = t & 63, w = t >> 6;
    const int n0 = blockIdx.x * 128;
    const int m0 = blockIdx.y * BM;
    const int wr = w >> 1, wc = w & 1, l15 = lane & 15, quad = lane >> 4;
    const int l7 = l15 & 7;

    f32x4 acc[MI][4];
    #pragma unroll
    for (int i = 0; i < MI; ++i)
        #pragma unroll
        for (int j = 0; j < 4; ++j)
            #pragma unroll
            for (int r = 0; r < 4; ++r) acc[i][j][r] = 0.f;

    for (int k0 = 0; k0 < K; k0 += 64) {
        #pragma unroll
        for (int i = 0; i < 4; ++i) {
            const int c = i * 256 + t;
            const int row = c >> 3;
            const int col = ((c & 7) ^ (row & 7)) * 8;
            const bf16* gb = Bt + (size_t)(n0 + row) * K + k0 + col;
            __builtin_amdgcn_global_load_lds(
                (const __attribute__((address_space(1))) void*)gb,
                (__attribute__((address_space(3))) void*)(Bs + (size_t)c * 8), 16, 0, 0);
            if (i < BM / 32) {
                const bf16* ga = A + (size_t)(m0 + row) * K + k0 + col;
                __builtin_amdgcn_global_load_lds(
                    (const __attribute__((address_space(1))) void*)ga,
                    (__attribute__((address_space(3))) void*)(As + (size_t)c * 8), 16, 0, 0);
            }
        }
        __syncthreads();
        #pragma unroll
        for (int kk = 0; kk < 2; ++kk) {
            const int sw = (((kk << 2) | quad) ^ l7) << 3;
            bf16x8 af[MI], bfr[4];
            #pragma unroll
            for (int mi = 0; mi < MI; ++mi)
                af[mi] = *(const bf16x8*)(As + (wr * (BM / 2) + mi * 16 + l15) * 64 + sw);
            #pragma unroll
            for (int ni = 0; ni < 4; ++ni)
                bfr[ni] = *(const bf16x8*)(Bs + (wc * 64 + ni * 16 + l15) * 64 + sw);
            #pragma unroll
            for (int mi = 0; mi < MI; ++mi)
                #pragma unroll
                for (int ni = 0; ni < 4; ++ni)
                    acc[mi][ni] = __builtin_amdgcn_mfma_f32_16x16x32_bf16(
                        af[mi], bfr[ni], acc[mi][ni], 0, 0, 0);
        }
        __syncthreads();
    }

    #pragma unroll
    for (int mi = 0; mi < MI; ++mi)
        #pragma unroll
        for (int ni = 0; ni < 4; ++ni) {
            const int col = n0 + wc * 64 + ni * 16 + l15;
            const float bv = bias[col];
            #pragma unroll
            for (int r = 0; r < 4; ++r) {
                const int row = m0 + wr * (BM / 2) + mi * 16 + quad * 4 + r;
                float v = acc[mi][ni][r] + bv;
                if (RELU) v = v > 0.f ? v : 0.f;
                if (EPI == 0) {
                    ((float*)outp)[(size_t)row * N + col] = v;
                } else if (EPI == 1) {
                    const bf16 hi = f2b(v);
                    const bf16 lo = f2b(v - b2f(hi));
                    bf16* o = (bf16*)outp + (size_t)row * 3 * N + 3 * col;
                    o[0] = hi; o[1] = hi; o[2] = lo;
                } else if (EPI == 2) {
                    ((bf16*)outp)[(size_t)row * N + col] = f2b(v);
                } else {
                    v = fminf(fmaxf(v, -1.f), 1.f);
                    ((float*)outp)[(size_t)row * N + col] = v;
                }
            }
        }
}

// ---------------------------------------------------------------------------
// VQ stage 2: one block per (expert, 32-row chunk). Grid 768 (3 x 256).
// ---------------------------------------------------------------------------
__global__ __launch_bounds__(256)
void vq2_kernel(const float* __restrict__ xe_buf, const float* __restrict__ cb,
                const float* __restrict__ cnorm, const float* __restrict__ Wout,
                const float* __restrict__ bout, float* __restrict__ qemb,
                float* __restrict__ idx_out, float* __restrict__ commit_acc)
{
    __shared__ float cb_s[256 * 36];   // padded: row stride 36 (16B-aligned, uniform banks)
    __shared__ float wo_s[32 * 128];
    __shared__ float cn_s[256];
    __shared__ float bo_s[128];
    __shared__ float xe_s[4 * 32];
    __shared__ float q_s[4 * 32];
    __shared__ int   idx_s[4];
    __shared__ u64   wred[4][4];
    __shared__ float cred[256];

    const int e  = blockIdx.x >> 8;        // 0..2
    const int rb = blockIdx.x & 255;       // 0..255 (32-row chunks)
    const int t = threadIdx.x, lane = t & 63, w = t >> 6;

    for (int j = t; j < 256 * 32; j += 256) {
        const int code = j >> 5, c = j & 31;
        cb_s[code * 36 + c] = cb[(size_t)e * 8192 + j];
    }
    for (int j = t; j < 4096; j += 256) wo_s[j] = Wout[(size_t)e * 4096 + j];
    cn_s[t] = cnorm[e * 256 + t];
    if (t < 128) bo_s[t] = bout[e * 128 + t];
    float commit_loc = 0.f;
    __syncthreads();

    for (int it = 0; it < 8; ++it) {
        const int r0 = rb * 32 + it * 4;
        if (t < 128) {
            const int r4 = t >> 5, c = t & 31;
            xe_s[r4 * 32 + c] = xe_buf[(size_t)(r0 + r4) * 128 + e * 32 + c];
        }
        __syncthreads();

        u64 key[4];
        {
            const float4* cp = (const float4*)(cb_s + t * 36);
            const float cn = cn_s[t];
            #pragma unroll
            for (int r4 = 0; r4 < 4; ++r4) {
                float dot = 0.f;
                #pragma unroll
                for (int c4 = 0; c4 < 8; ++c4) {
                    const float4 cv = cp[c4];
                    const float4 xv = *(const float4*)(xe_s + r4 * 32 + c4 * 4);
                    dot += xv.x * cv.x + xv.y * cv.y + xv.z * cv.z + xv.w * cv.w;
                }
                const float d = cn - 2.f * dot;
                u32 ub = __builtin_bit_cast(u32, d);
                ub = (ub & 0x80000000u) ? ~ub : (ub | 0x80000000u);
                key[r4] = ((u64)ub << 32) | (u32)t;
            }
        }
        #pragma unroll
        for (int off = 32; off; off >>= 1) {
            #pragma unroll
            for (int r4 = 0; r4 < 4; ++r4) {
                const u64 o = __shfl_down(key[r4], off, 64);
                if (o < key[r4]) key[r4] = o;
            }
        }
        if (lane == 0) {
            #pragma unroll
            for (int r4 = 0; r4 < 4; ++r4) wred[r4][w] = key[r4];
        }
        __syncthreads();
        if (t < 4) {
            u64 k = wred[t][0];
            #pragma unroll
            for (int ww = 1; ww < 4; ++ww) if (wred[t][ww] < k) k = wred[t][ww];
            const int code = (int)(k & 0xFFFFFFFFu);
            idx_s[t] = code;
            idx_out[(size_t)(r0 + t) * 3 + e] = (float)code;
        }
        __syncthreads();
        if (t < 128) {
            const int r4 = t >> 5, c = t & 31;
            const float q = cb_s[idx_s[r4] * 36 + c];
            q_s[r4 * 32 + c] = q;
            const float dd = q - xe_s[r4 * 32 + c];
            commit_loc += dd * dd;
        }
        __syncthreads();
        #pragma unroll
        for (int p = 0; p < 2; ++p) {
            const int j = p * 256 + t;
            const int r4 = j >> 7, h = j & 127;
            float s = bo_s[h];
            #pragma unroll
            for (int c = 0; c < 32; ++c) s += q_s[r4 * 32 + c] * wo_s[c * 128 + h];
            qemb[((size_t)e * 8192 + r0 + r4) * 128 + h] = s;
        }
        __syncthreads();
    }

    cred[t] = commit_loc;
    __syncthreads();
    for (int o = 128; o; o >>= 1) { if (t < o) cred[t] += cred[t + o]; __syncthreads(); }
    if (t == 0) atomicAdd(commit_acc, cred[0]);
}

// ---------------------------------------------------------------------------
// rl = mean_e qemb (bf16) + per-h expert sums for the decorrelation mean.
// ---------------------------------------------------------------------------
__global__ __launch_bounds__(256)
void rlmean_kernel(const float* __restrict__ qemb, bf16* __restrict__ rl,
                   float* __restrict__ meanAcc)
{
    const int t = threadIdx.x, h = t & 127, half = t >> 7;
    const int r0 = blockIdx.x * 64;
    float a0 = 0.f, a1 = 0.f, a2 = 0.f;
    for (int r = r0 + half; r < r0 + 64; r += 2) {
        const float v0 = qemb[((size_t)0 * 8192 + r) * 128 + h];
        const float v1 = qemb[((size_t)1 * 8192 + r) * 128 + h];
        const float v2 = qemb[((size_t)2 * 8192 + r) * 128 + h];
        a0 += v0; a1 += v1; a2 += v2;
        rl[(size_t)r * 128 + h] = f2b((v0 + v1 + v2) * (1.f / 3.f));
    }
    __shared__ float red[3][256];
    red[0][t] = a0; red[1][t] = a1; red[2][t] = a2;
    __syncthreads();
    if (t < 128) {
        atomicAdd(&meanAcc[0 * 128 + h], red[0][t] + red[0][t + 128]);
        atomicAdd(&meanAcc[1 * 128 + h], red[1][t] + red[1][t + 128]);
        atomicAdd(&meanAcc[2 * 128 + h], red[2][t] + red[2][t + 128]);
    }
}

__global__ __launch_bounds__(256)
void gram_kernel(const float* __restrict__ qemb, const float* __restrict__ meanAcc,
                 double* __restrict__ gram)
{
    const int t = threadIdx.x;
    const int h = t & 127, half = t >> 7;
    const int b0 = blockIdx.x * 32;
    const float m0 = meanAcc[0 * 128 + h] * (1.f / 8192.f);
    const float m1 = meanAcc[1 * 128 + h] * (1.f / 8192.f);
    const float m2 = meanAcc[2 * 128 + h] * (1.f / 8192.f);
    float g[6] = {0, 0, 0, 0, 0, 0};
    for (int b = b0 + half; b < b0 + 32; b += 2) {
        const float v0 = qemb[((size_t)0 * 8192 + b) * 128 + h] - m0;
        const float v1 = qemb[((size_t)1 * 8192 + b) * 128 + h] - m1;
        const float v2 = qemb[((size_t)2 * 8192 + b) * 128 + h] - m2;
        g[0] += v0 * v0; g[1] += v0 * v1; g[2] += v0 * v2;
        g[3] += v1 * v1; g[4] += v1 * v2; g[5] += v2 * v2;
    }
    __shared__ float red[256];
    for (int i = 0; i < 6; ++i) {
        red[t] = g[i];
        __syncthreads();
        for (int o = 128; o; o >>= 1) { if (t < o) red[t] += red[t + o]; __syncthreads(); }
        if (t == 0) atomicAdd(&gram[i], (double)red[0]);
        __syncthreads();
    }
}

__global__ void final_kernel(const float* __restrict__ commit_acc,
                             const double* __restrict__ gram,
                             float* __restrict__ out2)
{
    if (threadIdx.x != 0 || blockIdx.x != 0) return;
    const double denom = 8192.0 * 128.0 - 1.0;
    const double c00 = gram[0] / denom, c01 = gram[1] / denom, c02 = gram[2] / denom;
    const double c11 = gram[3] / denom, c12 = gram[4] / denom, c22 = gram[5] / denom;
    double s0 = sqrt(c00), s1 = sqrt(c11), s2 = sqrt(c22);
    if (!(s0 > 1e-8)) s0 = 1.0;
    if (!(s1 > 1e-8)) s1 = 1.0;
    if (!(s2 > 1e-8)) s2 = 1.0;
    const double r01 = c01 / (s0 * s1), r02 = c02 / (s0 * s2), r12 = c12 / (s1 * s2);
    const double decorr = 2.0 * (r01 * r01 + r02 * r02 + r12 * r12);
    out2[0] = (float)((double)commit_acc[0] * (0.25 / (8192.0 * 32.0)));
    out2[1] = (float)decorr;
}

// ---------------------------------------------------------------------------
extern "C" void kernel_launch(void* const* d_in, const int* in_sizes, int n_in,
                              void* d_out, int out_size, void* d_ws, size_t ws_size,
                              hipStream_t stream)
{
    const float* x    = (const float*)d_in[0];
    const float* Wd1  = (const float*)d_in[1];
    const float* bd1  = (const float*)d_in[2];
    const float* Wd2  = (const float*)d_in[3];
    const float* bd2  = (const float*)d_in[4];
    const float* Wd3  = (const float*)d_in[5];
    const float* bd3  = (const float*)d_in[6];
    const float* Win  = (const float*)d_in[7];
    const float* bin_ = (const float*)d_in[8];
    const float* cb   = (const float*)d_in[9];
    const float* Wout = (const float*)d_in[10];
    const float* bout = (const float*)d_in[11];
    const float* Wu1  = (const float*)d_in[12];
    const float* bu1  = (const float*)d_in[13];
    const float* Wu2  = (const float*)d_in[14];
    const float* bu2  = (const float*)d_in[15];
    const float* Wu3  = (const float*)d_in[16];
    const float* bu3  = (const float*)d_in[17];

    char* ws = (char*)d_ws;
    bf16*  Wd1s   = (bf16*)(ws + OFF_WD1S);
    bf16*  Wd2s   = (bf16*)(ws + OFF_WD2S);
    bf16*  WfuseS = (bf16*)(ws + OFF_WFUS);
    bf16*  Wu1T   = (bf16*)(ws + OFF_WU1T);
    bf16*  Wu2T   = (bf16*)(ws + OFF_WU2T);
    bf16*  Wu3T   = (bf16*)(ws + OFF_WU3T);
    bf16*  h1s    = (bf16*)(ws + OFF_H1S);
    bf16*  h2s    = (bf16*)(ws + OFF_H2S);
    float* xe     = (float*)(ws + OFF_XE);
    float* qemb   = (float*)(ws + OFF_QEMB);
    bf16*  rl     = (bf16*)(ws + OFF_RL);
    bf16*  u1     = (bf16*)(ws + OFF_U1);
    bf16*  u2     = (bf16*)(ws + OFF_U2);
    float* cnorm  = (float*)(ws + OFF_CNRM);
    float* bfuse  = (float*)(ws + OFF_BFUS);
    float* commit = (float*)(ws + OFF_STAT);
    double* gram  = (double*)(ws + OFF_STAT + 8);
    float* meanA  = (float*)(ws + OFF_STAT + 64);
    float* part   = (float*)(ws + OFF_PART);

    float* out_f   = (float*)d_out;
    float* idx_out = out_f + (size_t)8192 * 4096;
    float* scal    = idx_out + (size_t)8192 * 3;

    hipMemsetAsync(ws + OFF_STAT, 0, 2048, stream);

    const dim3 tb(32, 8);
    wtrans_hilo<<<dim3(16, 128), tb, 0, stream>>>(Wd1, Wd1s, 4096, 512);
    wtrans_split3<<<dim3(8, 16),   tb, 0, stream>>>(Wd2, Wd2s, 512, 256);
    wtrans_bf16<<<dim3(8, 4),      tb, 0, stream>>>(Wu1, Wu1T, 128, 256);
    wtrans_bf16<<<dim3(16, 8),     tb, 0, stream>>>(Wu2, Wu2T, 256, 512);
    wtrans_bf16<<<dim3(128, 16),   tb, 0, stream>>>(Wu3, Wu3T, 512, 4096);
    cnorm_kernel<<<3, 256, 0, stream>>>(cb, cnorm);
    wfuse_kernel<<<128, 256, 0, stream>>>(Wd3, bd3, Win, bin_, WfuseS, bfuse);

    // down MLP (split bf16, ~f32 accuracy) ending directly in xe = latent@Win+...
    gemm1_x3<<<dim3(4, 64, 4), 256, 0, stream>>>(x, Wd1s, part);
    h1_epi<<<4096, 256, 0, stream>>>(part, bd1, h1s);
    gemm_bt<1, 1, 64><<<dim3(2, 128), 256, 0, stream>>>(h1s, Wd2s, bd2, h2s, 8192, 256, 1536);
    gemm_bt<0, 0, 64><<<dim3(1, 128), 256, 0, stream>>>(h2s, WfuseS, bfuse, xe, 8192, 128, 768);

    vq2_kernel<<<768, 256, 0, stream>>>(xe, cb, cnorm, Wout, bout, qemb, idx_out, commit);
    rlmean_kernel<<<128, 256, 0, stream>>>(qemb, rl, meanA);
    gram_kernel<<<256, 256, 0, stream>>>(qemb, meanA, gram);
    final_kernel<<<1, 64, 0, stream>>>(commit, gram, scal);

    // up MLP: plain bf16 compute, f32 recon out
    gemm_bt<2, 1, 64><<<dim3(2, 128),  256, 0, stream>>>(rl, Wu1T, bu1, u1,    8192, 256,  128);
    gemm_bt<2, 1, 64><<<dim3(4, 128),  256, 0, stream>>>(u1, Wu2T, bu2, u2,    8192, 512,  256);
    gemm_bt<3, 0, 128><<<dim3(32, 64), 256, 0, stream>>>(u2, Wu3T, bu3, out_f, 8192, 4096, 512);

    (void)in_sizes; (void)n_in; (void)out_size; (void)ws_size;
}

// Round 8
// 566.650 us; speedup vs baseline: 1.9227x; 1.1554x over previous
//
#include <hip/hip_runtime.h>
#include <hip/hip_bf16.h>

using bf16 = __hip_bfloat16;

typedef __bf16 bf16x8 __attribute__((ext_vector_type(8)));
typedef float  f32x4  __attribute__((ext_vector_type(4)));
typedef unsigned int u32x4 __attribute__((ext_vector_type(4)));
typedef unsigned long long u64;
typedef unsigned short u16;
typedef unsigned int u32;

__device__ __forceinline__ float b2f(bf16 v) { return __bfloat162float(v); }
__device__ __forceinline__ bf16  f2b(float v) { return __float2bfloat16(v); }
__device__ __forceinline__ u16   bits(bf16 v) { return __builtin_bit_cast(u16, v); }

// ---------------------------------------------------------------------------
// Workspace layout
// ---------------------------------------------------------------------------
static constexpr size_t SZ_WD1S = 512ull  * 8192  * 2;  // bf16 [512][128 kg][hi32|lo32]
static constexpr size_t SZ_WD2S = 256ull  * 1536  * 2;  // bf16 [256][3*512] split3
static constexpr size_t SZ_WFUS = 128ull  * 768   * 2;  // bf16 [128][3*256] (Wd3@Win fused, split3)
static constexpr size_t SZ_WU1T = 256ull  * 128   * 2;
static constexpr size_t SZ_WU2T = 512ull  * 256   * 2;
static constexpr size_t SZ_WU3T = 4096ull * 512   * 2;
static constexpr size_t SZ_H1S  = 8192ull * 1536  * 2;  // bf16 [8192][3*512] (hi,hi,lo)
static constexpr size_t SZ_H2S  = 8192ull * 768   * 2;  // bf16 [8192][3*256]
static constexpr size_t SZ_XE   = 8192ull * 128   * 4;  // f32 xe (cols e*32+c, 96..127 unused)
static constexpr size_t SZ_QEMB = 3ull * 8192 * 128 * 4;// f32
static constexpr size_t SZ_RL   = 8192ull * 128   * 2;  // bf16
static constexpr size_t SZ_U1   = 8192ull * 256   * 2;
static constexpr size_t SZ_U2   = 8192ull * 512   * 2;
static constexpr size_t SZ_CNRM = 768ull * 4;
static constexpr size_t SZ_BFUS = 128ull * 4;
static constexpr size_t SZ_PART = 4ull * 8192 * 512 * 4; // f32 K-split partials (4 slabs)

static constexpr size_t OFF_WD1S = 0;
static constexpr size_t OFF_WD2S = OFF_WD1S + SZ_WD1S;
static constexpr size_t OFF_WFUS = OFF_WD2S + SZ_WD2S;
static constexpr size_t OFF_WU1T = OFF_WFUS + SZ_WFUS;
static constexpr size_t OFF_WU2T = OFF_WU1T + SZ_WU1T;
static constexpr size_t OFF_WU3T = OFF_WU2T + SZ_WU2T;
static constexpr size_t OFF_H1S  = OFF_WU3T + SZ_WU3T;
static constexpr size_t OFF_H2S  = OFF_H1S  + SZ_H1S;
static constexpr size_t OFF_XE   = OFF_H2S  + SZ_H2S;
static constexpr size_t OFF_QEMB = OFF_XE   + SZ_XE;
static constexpr size_t OFF_RL   = OFF_QEMB + SZ_QEMB;
static constexpr size_t OFF_U1   = OFF_RL   + SZ_RL;
static constexpr size_t OFF_U2   = OFF_U1   + SZ_U1;
static constexpr size_t OFF_CNRM = OFF_U2   + SZ_U2;
static constexpr size_t OFF_BFUS = OFF_CNRM + ((SZ_CNRM + 255) & ~size_t(255));
static constexpr size_t OFF_STAT = OFF_BFUS + ((SZ_BFUS + 255) & ~size_t(255));
// stats (memset 0 each launch): +0 f32 commit; +8 double gram[6]; +64 f32 meanAcc[384]
static constexpr size_t OFF_PART = OFF_STAT + 2048;

// ---------------------------------------------------------------------------
// Weight transposes: in [K][N] f32.
// ---------------------------------------------------------------------------
__global__ void wtrans_bf16(const float* __restrict__ in, bf16* __restrict__ out,
                            int K, int N)
{
    __shared__ float tile[32][33];
    const int tx = threadIdx.x, ty = threadIdx.y;
    const int n0 = blockIdx.x * 32, k0 = blockIdx.y * 32;
    #pragma unroll
    for (int i = 0; i < 32; i += 8)
        tile[ty + i][tx] = in[(size_t)(k0 + ty + i) * N + n0 + tx];
    __syncthreads();
    #pragma unroll
    for (int i = 0; i < 32; i += 8)
        out[(size_t)(n0 + ty + i) * K + k0 + tx] = f2b(tile[tx][ty + i]);
}

__global__ void wtrans_split3(const float* __restrict__ in, bf16* __restrict__ out,
                              int K, int N)
{
    __shared__ float tile[32][33];
    const int tx = threadIdx.x, ty = threadIdx.y;
    const int n0 = blockIdx.x * 32, k0 = blockIdx.y * 32;
    #pragma unroll
    for (int i = 0; i < 32; i += 8)
        tile[ty + i][tx] = in[(size_t)(k0 + ty + i) * N + n0 + tx];
    __syncthreads();
    #pragma unroll
    for (int i = 0; i < 32; i += 8) {
        const float v = tile[tx][ty + i];
        const bf16 hi = f2b(v);
        const bf16 lo = f2b(v - b2f(hi));
        bf16* o = out + (size_t)(n0 + ty + i) * 3 * K + 3 * (k0 + tx);
        o[0] = hi; o[1] = lo; o[2] = hi;
    }
}

// Wd1 -> [n 0..511][kg 0..127][slot: hi k&31 | 32+ lo k&31]
__global__ void wtrans_hilo(const float* __restrict__ in, bf16* __restrict__ out,
                            int K, int N)
{
    __shared__ float tile[32][33];
    const int tx = threadIdx.x, ty = threadIdx.y;
    const int n0 = blockIdx.x * 32, k0 = blockIdx.y * 32;
    #pragma unroll
    for (int i = 0; i < 32; i += 8)
        tile[ty + i][tx] = in[(size_t)(k0 + ty + i) * N + n0 + tx];
    __syncthreads();
    const int kg = k0 >> 5;
    #pragma unroll
    for (int i = 0; i < 32; i += 8) {
        const float v = tile[tx][ty + i];
        const bf16 hi = f2b(v);
        const bf16 lo = f2b(v - b2f(hi));
        bf16* o = out + (size_t)(n0 + ty + i) * 8192 + kg * 64 + tx;
        o[0] = hi; o[32] = lo;
    }
}

__global__ void cnorm_kernel(const float* __restrict__ cb, float* __restrict__ cnorm)
{
    const int i = blockIdx.x * blockDim.x + threadIdx.x;
    if (i < 768) {
        float s = 0.f;
        for (int k = 0; k < 32; ++k) { const float v = cb[i * 32 + k]; s += v * v; }
        cnorm[i] = s;
    }
}

// ---------------------------------------------------------------------------
// Fused VQ projection weights: Wfuse[n=e*32+c][d2] = sum_h Wd3[d2][h]*Win[e][h][c]
// emitted split3 (hi,lo,hi) as B-side for gemm_bt; rows 96..127 zero.
// ---------------------------------------------------------------------------
__global__ __launch_bounds__(256)
void wfuse_kernel(const float* __restrict__ Wd3, const float* __restrict__ bd3,
                  const float* __restrict__ Win, const float* __restrict__ bin_,
                  bf16* __restrict__ BtS, float* __restrict__ bfuse)
{
    const int n = blockIdx.x;       // 0..127
    const int t = threadIdx.x;      // 0..255 == d2
    if (n >= 96) {
        bf16* o = BtS + (size_t)n * 768 + 3 * t;
        o[0] = f2b(0.f); o[1] = f2b(0.f); o[2] = f2b(0.f);
        if (t == 0) bfuse[n] = 0.f;
        return;
    }
    const int e = n >> 5, c = n & 31;
    float s = 0.f;
    for (int h = 0; h < 128; ++h)
        s += Wd3[t * 128 + h] * Win[(size_t)(e * 128 + h) * 32 + c];
    const bf16 hi = f2b(s);
    const bf16 lo = f2b(s - b2f(hi));
    bf16* o = BtS + (size_t)n * 768 + 3 * t;
    o[0] = hi; o[1] = lo; o[2] = hi;
    if (t == 0) {
        float b = bin_[e * 32 + c];
        for (int h = 0; h < 128; ++h)
            b += bd3[h] * Win[(size_t)(e * 128 + h) * 32 + c];
        bfuse[n] = b;
    }
}

// ---------------------------------------------------------------------------
// Layer-1 GEMM with on-the-fly hi/lo split of A = x (f32).
// v8 = v5 verbatim (measured 131 us / FETCH 267 MB): the v7 register
// A-prefetch caused scratch spills (FETCH +70 MB, dur +70 us) — reverted.
// As/Bs [128 rows][64 slots] bf16 (hi 0-31 | lo 32-63), XOR-swizzled 16B
// chunks; 32 KB LDS -> 4 blocks/CU, grid 1024 fully resident;
// v5 XCD-panel remap.
// ---------------------------------------------------------------------------
__global__ __launch_bounds__(256, 4)
void gemm1_x3(const float* __restrict__ A, const bf16* __restrict__ Bhl,
              float* __restrict__ part)
{
    __shared__ bf16 As[128 * 64];
    __shared__ bf16 Bs[128 * 64];
    const int t = threadIdx.x, lane = t & 63, w = t >> 6;
    // v5 XCD-panel remap (measured: 131 us, FETCH 267 MB)
    const int bid = blockIdx.x + blockIdx.y * 4 + blockIdx.z * 256;  // 0..1023
    const int xcd = bid & 7, j = bid >> 3;                           // 0..7, 0..127
    const int panel = xcd + 8 * (j >> 6);                            // 0..15
    const int n0 = (panel & 3) * 128;
    const int kz = panel >> 2;
    const int m0 = (j & 63) * 128;
    const int wr = w >> 1, wc = w & 1, l15 = lane & 15, quad = lane >> 4;
    const int offh = ((quad ^ (l15 & 7)) << 3);
    const int offl = offh ^ 32;

    f32x4 acc[4][4];
    #pragma unroll
    for (int i = 0; i < 4; ++i)
        #pragma unroll
        for (int jj = 0; jj < 4; ++jj)
            #pragma unroll
            for (int rr = 0; rr < 4; ++rr) acc[i][jj][rr] = 0.f;

    // A-pack mapping: row = t>>1, half = t&1 (16 consecutive f32 each)
    const int arow = t >> 1, ahalf = t & 1, arx = arow & 7;
    bf16* const aw0 = As + arow * 64 + (((ahalf * 2 + 0) ^ arx) << 3);        // hi chunk
    bf16* const aw1 = As + arow * 64 + (((ahalf * 2 + 1) ^ arx) << 3);        // hi chunk
    bf16* const aw2 = As + arow * 64 + (((4 + ahalf * 2 + 0) ^ arx) << 3);    // lo chunk
    bf16* const aw3 = As + arow * 64 + (((4 + ahalf * 2 + 1) ^ arx) << 3);    // lo chunk

    // B loader: physical chunk p -> row = p>>3, logical chunk = (p&7)^(row&7)
    int brow[4], bco[4];
    #pragma unroll
    for (int i = 0; i < 4; ++i) {
        const int p = i * 256 + t;
        brow[i] = p >> 3;
        bco[i] = ((p & 7) ^ (brow[i] & 7)) * 8;
    }

    const int s0 = kz * 32, s1 = s0 + 32;
    for (int ks = s0; ks < s1; ++ks) {
        // A global loads first (feed the VALU pack)
        const float* ap = A + (size_t)(m0 + arow) * 4096 + ks * 32 + ahalf * 16;
        float f[16];
        *(float4*)(f + 0)  = *(const float4*)(ap + 0);
        *(float4*)(f + 4)  = *(const float4*)(ap + 4);
        *(float4*)(f + 8)  = *(const float4*)(ap + 8);
        *(float4*)(f + 12) = *(const float4*)(ap + 12);
        // B global->LDS (async, drains at the barrier)
        #pragma unroll
        for (int i = 0; i < 4; ++i) {
            const bf16* gb = Bhl + (size_t)(n0 + brow[i]) * 8192 + ks * 64 + bco[i];
            __builtin_amdgcn_global_load_lds(
                (const __attribute__((address_space(1))) void*)gb,
                (__attribute__((address_space(3))) void*)(Bs + (size_t)(i * 256 + t) * 8), 16, 0, 0);
        }
        // split + pack A: per 8-float group emit one hi chunk and one lo chunk
        {
            u32x4 hv, lv;
            #pragma unroll
            for (int jj = 0; jj < 4; ++jj) {
                const bf16 h0 = f2b(f[2 * jj]), h1 = f2b(f[2 * jj + 1]);
                const u32 l0 = bits(f2b(f[2 * jj] - b2f(h0)));
                const u32 l1 = bits(f2b(f[2 * jj + 1] - b2f(h1)));
                hv[jj] = (u32)bits(h0) | ((u32)bits(h1) << 16);
                lv[jj] = l0 | (l1 << 16);
            }
            *(u32x4*)aw0 = hv; *(u32x4*)aw2 = lv;
            #pragma unroll
            for (int jj = 0; jj < 4; ++jj) {
                const bf16 h0 = f2b(f[8 + 2 * jj]), h1 = f2b(f[8 + 2 * jj + 1]);
                const u32 l0 = bits(f2b(f[8 + 2 * jj] - b2f(h0)));
                const u32 l1 = bits(f2b(f[8 + 2 * jj + 1] - b2f(h1)));
                hv[jj] = (u32)bits(h0) | ((u32)bits(h1) << 16);
                lv[jj] = l0 | (l1 << 16);
            }
            *(u32x4*)aw1 = hv; *(u32x4*)aw3 = lv;
        }
        __syncthreads();
        {
            bf16x8 ah[4], al[4];
            #pragma unroll
            for (int mi = 0; mi < 4; ++mi) {
                const bf16* ar = As + (wr * 64 + mi * 16 + l15) * 64;
                ah[mi] = *(const bf16x8*)(ar + offh);
                al[mi] = *(const bf16x8*)(ar + offl);
            }
            #pragma unroll
            for (int ni = 0; ni < 4; ++ni) {
                const bf16* br = Bs + (wc * 64 + ni * 16 + l15) * 64;
                const bf16x8 bh = *(const bf16x8*)(br + offh);
                const bf16x8 bl = *(const bf16x8*)(br + offl);
                #pragma unroll
                for (int mi = 0; mi < 4; ++mi) {
                    acc[mi][ni] = __builtin_amdgcn_mfma_f32_16x16x32_bf16(ah[mi], bh, acc[mi][ni], 0, 0, 0);
                    acc[mi][ni] = __builtin_amdgcn_mfma_f32_16x16x32_bf16(al[mi], bh, acc[mi][ni], 0, 0, 0);
                    acc[mi][ni] = __builtin_amdgcn_mfma_f32_16x16x32_bf16(ah[mi], bl, acc[mi][ni], 0, 0, 0);
                }
            }
        }
        __syncthreads();
    }

    float* op = part + (size_t)kz * (8192ull * 512);
    #pragma unroll
    for (int mi = 0; mi < 4; ++mi)
        #pragma unroll
        for (int ni = 0; ni < 4; ++ni) {
            const int col = n0 + wc * 64 + ni * 16 + l15;
            #pragma unroll
            for (int rr = 0; rr < 4; ++rr) {
                const int row = m0 + wr * 64 + mi * 16 + quad * 4 + rr;
                op[(size_t)row * 512 + col] = acc[mi][ni][rr];
            }
        }
}

// ---------------------------------------------------------------------------
// Layer-1 epilogue: sum 4 K-split partials + bias, ReLU, emit split3 (hi,hi,lo).
// ---------------------------------------------------------------------------
__global__ __launch_bounds__(256)
void h1_epi(const float* __restrict__ part, const float* __restrict__ bias,
            bf16* __restrict__ out)
{
    const int idx = blockIdx.x * 256 + threadIdx.x;   // 0 .. 8192*128-1
    const int r = idx >> 7, c4 = idx & 127;
    const size_t base = (size_t)r * 512 + c4 * 4;
    const float4 p0 = *(const float4*)(part + 0ull * 8192 * 512 + base);
    const float4 p1 = *(const float4*)(part + 1ull * 8192 * 512 + base);
    const float4 p2 = *(const float4*)(part + 2ull * 8192 * 512 + base);
    const float4 p3 = *(const float4*)(part + 3ull * 8192 * 512 + base);
    const float4 bv = *(const float4*)(bias + c4 * 4);
    float v[4];
    v[0] = p0.x + p1.x + p2.x + p3.x + bv.x;
    v[1] = p0.y + p1.y + p2.y + p3.y + bv.y;
    v[2] = p0.z + p1.z + p2.z + p3.z + bv.z;
    v[3] = p0.w + p1.w + p2.w + p3.w + bv.w;
    u64 h[4], l[4];
    #pragma unroll
    for (int j = 0; j < 4; ++j) {
        const float vv = v[j] > 0.f ? v[j] : 0.f;
        const bf16 hi = f2b(vv);
        h[j] = bits(hi);
        l[j] = bits(f2b(vv - b2f(hi)));
    }
    const u64 w0 = h[0] | (h[0] << 16) | (l[0] << 32) | (h[1] << 48);
    const u64 w1 = h[1] | (l[1] << 16) | (h[2] << 32) | (h[2] << 48);
    const u64 w2 = l[2] | (h[3] << 16) | (h[3] << 32) | (l[3] << 48);
    u64* dst = (u64*)(out + (size_t)r * 1536 + 12 * c4);
    dst[0] = w0; dst[1] = w1; dst[2] = w2;
}

// ---------------------------------------------------------------------------
// Generic bf16 MFMA GEMM, tile BM x 128 (BM = 128 or 64).
// EPI: 0 = f32 out; 1 = split3 bf16 (hi,hi,lo, ldc=3N); 2 = bf16 out;
// 3 = f32 out with clip[-1,1].  Grid: (N/128, M/BM).
// ---------------------------------------------------------------------------
template <int EPI, int RELU, int BM>
__global__ __launch_bounds__(256)
void gemm_bt(const bf16* __restrict__ A, const bf16* __restrict__ Bt,
             const float* __restrict__ bias, void* __restrict__ outp,
             int M, int N, int K)
{
    constexpr int MI = BM / 32;            // m-fragments per wave
    __shared__ bf16 As[BM * 64];
    __shared__ bf16 Bs[128 * 64];
    const int t = threadIdx.x, lane = t & 63, w = t >> 6;
    const int n0 = blockIdx.x * 128;
    const int m0 = blockIdx.y * BM;
    const int wr = w >> 1, wc = w & 1, l15 = lane & 15, quad = lane >> 4;
    const int l7 = l15 & 7;

    f32x4 acc[MI][4];
    #pragma unroll
    for (int i = 0; i < MI; ++i)
        #pragma unroll
        for (int j = 0; j < 4; ++j)
            #pragma unroll
            for (int r = 0; r < 4; ++r) acc[i][j][r] = 0.f;

    for (int k0 = 0; k0 < K; k0 += 64) {
        #pragma unroll
        for (int i = 0; i < 4; ++i) {
            const int c = i * 256 + t;
            const int row = c >> 3;
            const int col = ((c & 7) ^ (row & 7)) * 8;
            const bf16* gb = Bt + (size_t)(n0 + row) * K + k0 + col;
            __builtin_amdgcn_global_load_lds(
                (const __attribute__((address_space(1))) void*)gb,
                (__attribute__((address_space(3))) void*)(Bs + (size_t)c * 8), 16, 0, 0);
            if (i < BM / 32) {
                const bf16* ga = A + (size_t)(m0 + row) * K + k0 + col;
                __builtin_amdgcn_global_load_lds(
                    (const __attribute__((address_space(1))) void*)ga,
                    (__attribute__((address_space(3))) void*)(As + (size_t)c * 8), 16, 0, 0);
            }
        }
        __syncthreads();
        #pragma unroll
        for (int kk = 0; kk < 2; ++kk) {
            const int sw = (((kk << 2) | quad) ^ l7) << 3;
            bf16x8 af[MI], bfr[4];
            #pragma unroll
            for (int mi = 0; mi < MI; ++mi)
                af[mi] = *(const bf16x8*)(As + (wr * (BM / 2) + mi * 16 + l15) * 64 + sw);
            #pragma unroll
            for (int ni = 0; ni < 4; ++ni)
                bfr[ni] = *(const bf16x8*)(Bs + (wc * 64 + ni * 16 + l15) * 64 + sw);
            #pragma unroll
            for (int mi = 0; mi < MI; ++mi)
                #pragma unroll
                for (int ni = 0; ni < 4; ++ni)
                    acc[mi][ni] = __builtin_amdgcn_mfma_f32_16x16x32_bf16(
                        af[mi], bfr[ni], acc[mi][ni], 0, 0, 0);
        }
        __syncthreads();
    }

    #pragma unroll
    for (int mi = 0; mi < MI; ++mi)
        #pragma unroll
        for (int ni = 0; ni < 4; ++ni) {
            const int col = n0 + wc * 64 + ni * 16 + l15;
            const float bv = bias[col];
            #pragma unroll
            for (int r = 0; r < 4; ++r) {
                const int row = m0 + wr * (BM / 2) + mi * 16 + quad * 4 + r;
                float v = acc[mi][ni][r] + bv;
                if (RELU) v = v > 0.f ? v : 0.f;
                if (EPI == 0) {
                    ((float*)outp)[(size_t)row * N + col] = v;
                } else if (EPI == 1) {
                    const bf16 hi = f2b(v);
                    const bf16 lo = f2b(v - b2f(hi));
                    bf16* o = (bf16*)outp + (size_t)row * 3 * N + 3 * col;
                    o[0] = hi; o[1] = hi; o[2] = lo;
                } else if (EPI == 2) {
                    ((bf16*)outp)[(size_t)row * N + col] = f2b(v);
                } else {
                    v = fminf(fmaxf(v, -1.f), 1.f);
                    ((float*)outp)[(size_t)row * N + col] = v;
                }
            }
        }
}

// ---------------------------------------------------------------------------
// VQ stage 2: one block per (expert, 32-row chunk). Grid 768 (3 x 256).
// ---------------------------------------------------------------------------
__global__ __launch_bounds__(256)
void vq2_kernel(const float* __restrict__ xe_buf, const float* __restrict__ cb,
                const float* __restrict__ cnorm, const float* __restrict__ Wout,
                const float* __restrict__ bout, float* __restrict__ qemb,
                float* __restrict__ idx_out, float* __restrict__ commit_acc)
{
    __shared__ float cb_s[256 * 36];   // padded: row stride 36 (16B-aligned, uniform banks)
    __shared__ float wo_s[32 * 128];
    __shared__ float cn_s[256];
    __shared__ float bo_s[128];
    __shared__ float xe_s[4 * 32];
    __shared__ float q_s[4 * 32];
    __shared__ int   idx_s[4];
    __shared__ u64   wred[4][4];
    __shared__ float cred[256];

    const int e  = blockIdx.x >> 8;        // 0..2
    const int rb = blockIdx.x & 255;       // 0..255 (32-row chunks)
    const int t = threadIdx.x, lane = t & 63, w = t >> 6;

    for (int j = t; j < 256 * 32; j += 256) {
        const int code = j >> 5, c = j & 31;
        cb_s[code * 36 + c] = cb[(size_t)e * 8192 + j];
    }
    for (int j = t; j < 4096; j += 256) wo_s[j] = Wout[(size_t)e * 4096 + j];
    cn_s[t] = cnorm[e * 256 + t];
    if (t < 128) bo_s[t] = bout[e * 128 + t];
    float commit_loc = 0.f;
    __syncthreads();

    for (int it = 0; it < 8; ++it) {
        const int r0 = rb * 32 + it * 4;
        if (t < 128) {
            const int r4 = t >> 5, c = t & 31;
            xe_s[r4 * 32 + c] = xe_buf[(size_t)(r0 + r4) * 128 + e * 32 + c];
        }
        __syncthreads();

        u64 key[4];
        {
            const float4* cp = (const float4*)(cb_s + t * 36);
            const float cn = cn_s[t];
            #pragma unroll
            for (int r4 = 0; r4 < 4; ++r4) {
                float dot = 0.f;
                #pragma unroll
                for (int c4 = 0; c4 < 8; ++c4) {
                    const float4 cv = cp[c4];
                    const float4 xv = *(const float4*)(xe_s + r4 * 32 + c4 * 4);
                    dot += xv.x * cv.x + xv.y * cv.y + xv.z * cv.z + xv.w * cv.w;
                }
                const float d = cn - 2.f * dot;
                u32 ub = __builtin_bit_cast(u32, d);
                ub = (ub & 0x80000000u) ? ~ub : (ub | 0x80000000u);
                key[r4] = ((u64)ub << 32) | (u32)t;
            }
        }
        #pragma unroll
        for (int off = 32; off; off >>= 1) {
            #pragma unroll
            for (int r4 = 0; r4 < 4; ++r4) {
                const u64 o = __shfl_down(key[r4], off, 64);
                if (o < key[r4]) key[r4] = o;
            }
        }
        if (lane == 0) {
            #pragma unroll
            for (int r4 = 0; r4 < 4; ++r4) wred[r4][w] = key[r4];
        }
        __syncthreads();
        if (t < 4) {
            u64 k = wred[t][0];
            #pragma unroll
            for (int ww = 1; ww < 4; ++ww) if (wred[t][ww] < k) k = wred[t][ww];
            const int code = (int)(k & 0xFFFFFFFFu);
            idx_s[t] = code;
            idx_out[(size_t)(r0 + t) * 3 + e] = (float)code;
        }
        __syncthreads();
        if (t < 128) {
            const int r4 = t >> 5, c = t & 31;
            const float q = cb_s[idx_s[r4] * 36 + c];
            q_s[r4 * 32 + c] = q;
            const float dd = q - xe_s[r4 * 32 + c];
            commit_loc += dd * dd;
        }
        __syncthreads();
        #pragma unroll
        for (int p = 0; p < 2; ++p) {
            const int j = p * 256 + t;
            const int r4 = j >> 7, h = j & 127;
            float s = bo_s[h];
            #pragma unroll
            for (int c = 0; c < 32; ++c) s += q_s[r4 * 32 + c] * wo_s[c * 128 + h];
            qemb[((size_t)e * 8192 + r0 + r4) * 128 + h] = s;
        }
        __syncthreads();
    }

    cred[t] = commit_loc;
    __syncthreads();
    for (int o = 128; o; o >>= 1) { if (t < o) cred[t] += cred[t + o]; __syncthreads(); }
    if (t == 0) atomicAdd(commit_acc, cred[0]);
}

// ---------------------------------------------------------------------------
// Fused rl-mean + raw Gram pass over qemb (one read instead of two).
// rl = mean_e qemb (bf16); meanAcc[e][h] += sum_r v_e; gram_raw[6] +=
// sum_{r,h} v_a v_b.  Mean-centering applied analytically in final_kernel:
// sum (v_a - m_a)(v_b - m_b) = G_ab - sum_h meanA_a[h]*meanA_b[h]/8192.
// Grid 256 x 256 (32 rows per block).
// ---------------------------------------------------------------------------
__global__ __launch_bounds__(256)
void rlgram_kernel(const float* __restrict__ qemb, bf16* __restrict__ rl,
                   float* __restrict__ meanAcc, double* __restrict__ gram)
{
    const int t = threadIdx.x, h = t & 127, half = t >> 7;
    const int r0 = blockIdx.x * 32;
    float a0 = 0.f, a1 = 0.f, a2 = 0.f;
    float g[6] = {0, 0, 0, 0, 0, 0};
    for (int r = r0 + half; r < r0 + 32; r += 2) {
        const float v0 = qemb[((size_t)0 * 8192 + r) * 128 + h];
        const float v1 = qemb[((size_t)1 * 8192 + r) * 128 + h];
        const float v2 = qemb[((size_t)2 * 8192 + r) * 128 + h];
        a0 += v0; a1 += v1; a2 += v2;
        g[0] += v0 * v0; g[1] += v0 * v1; g[2] += v0 * v2;
        g[3] += v1 * v1; g[4] += v1 * v2; g[5] += v2 * v2;
        rl[(size_t)r * 128 + h] = f2b((v0 + v1 + v2) * (1.f / 3.f));
    }
    __shared__ float red3[3][256];
    red3[0][t] = a0; red3[1][t] = a1; red3[2][t] = a2;
    __syncthreads();
    if (t < 128) {
        atomicAdd(&meanAcc[0 * 128 + h], red3[0][t] + red3[0][t + 128]);
        atomicAdd(&meanAcc[1 * 128 + h], red3[1][t] + red3[1][t + 128]);
        atomicAdd(&meanAcc[2 * 128 + h], red3[2][t] + red3[2][t + 128]);
    }
    __syncthreads();
    __shared__ float red[256];
    for (int i = 0; i < 6; ++i) {
        red[t] = g[i];
        __syncthreads();
        for (int o = 128; o; o >>= 1) { if (t < o) red[t] += red[t + o]; __syncthreads(); }
        if (t == 0) atomicAdd(&gram[i], (double)red[0]);
        __syncthreads();
    }
}

__global__ void final_kernel(const float* __restrict__ commit_acc,
                             const double* __restrict__ gram,
                             const float* __restrict__ meanAcc,
                             float* __restrict__ out2)
{
    if (threadIdx.x != 0 || blockIdx.x != 0) return;
    // mean-correction: cen_ab = gram_ab - sum_h meanA_a[h]*meanA_b[h] / 8192
    double corr[6] = {0, 0, 0, 0, 0, 0};
    for (int h = 0; h < 128; ++h) {
        const double m0 = meanAcc[0 * 128 + h];
        const double m1 = meanAcc[1 * 128 + h];
        const double m2 = meanAcc[2 * 128 + h];
        corr[0] += m0 * m0; corr[1] += m0 * m1; corr[2] += m0 * m2;
        corr[3] += m1 * m1; corr[4] += m1 * m2; corr[5] += m2 * m2;
    }
    const double denom = 8192.0 * 128.0 - 1.0;
    const double c00 = (gram[0] - corr[0] / 8192.0) / denom;
    const double c01 = (gram[1] - corr[1] / 8192.0) / denom;
    const double c02 = (gram[2] - corr[2] / 8192.0) / denom;
    const double c11 = (gram[3] - corr[3] / 8192.0) / denom;
    const double c12 = (gram[4] - corr[4] / 8192.0) / denom;
    const double c22 = (gram[5] - corr[5] / 8192.0) / denom;
    double s0 = sqrt(c00), s1 = sqrt(c11), s2 = sqrt(c22);
    if (!(s0 > 1e-8)) s0 = 1.0;
    if (!(s1 > 1e-8)) s1 = 1.0;
    if (!(s2 > 1e-8)) s2 = 1.0;
    const double r01 = c01 / (s0 * s1), r02 = c02 / (s0 * s2), r12 = c12 / (s1 * s2);
    const double decorr = 2.0 * (r01 * r01 + r02 * r02 + r12 * r12);
    out2[0] = (float)((double)commit_acc[0] * (0.25 / (8192.0 * 32.0)));
    out2[1] = (float)decorr;
}

// ---------------------------------------------------------------------------
extern "C" void kernel_launch(void* const* d_in, const int* in_sizes, int n_in,
                              void* d_out, int out_size, void* d_ws, size_t ws_size,
                              hipStream_t stream)
{
    const float* x    = (const float*)d_in[0];
    const float* Wd1  = (const float*)d_in[1];
    const float* bd1  = (const float*)d_in[2];
    const float* Wd2  = (const float*)d_in[3];
    const float* bd2  = (const float*)d_in[4];
    const float* Wd3  = (const float*)d_in[5];
    const float* bd3  = (const float*)d_in[6];
    const float* Win  = (const float*)d_in[7];
    const float* bin_ = (const float*)d_in[8];
    const float* cb   = (const float*)d_in[9];
    const float* Wout = (const float*)d_in[10];
    const float* bout = (const float*)d_in[11];
    const float* Wu1  = (const float*)d_in[12];
    const float* bu1  = (const float*)d_in[13];
    const float* Wu2  = (const float*)d_in[14];
    const float* bu2  = (const float*)d_in[15];
    const float* Wu3  = (const float*)d_in[16];
    const float* bu3  = (const float*)d_in[17];

    char* ws = (char*)d_ws;
    bf16*  Wd1s   = (bf16*)(ws + OFF_WD1S);
    bf16*  Wd2s   = (bf16*)(ws + OFF_WD2S);
    bf16*  WfuseS = (bf16*)(ws + OFF_WFUS);
    bf16*  Wu1T   = (bf16*)(ws + OFF_WU1T);
    bf16*  Wu2T   = (bf16*)(ws + OFF_WU2T);
    bf16*  Wu3T   = (bf16*)(ws + OFF_WU3T);
    bf16*  h1s    = (bf16*)(ws + OFF_H1S);
    bf16*  h2s    = (bf16*)(ws + OFF_H2S);
    float* xe     = (float*)(ws + OFF_XE);
    float* qemb   = (float*)(ws + OFF_QEMB);
    bf16*  rl     = (bf16*)(ws + OFF_RL);
    bf16*  u1     = (bf16*)(ws + OFF_U1);
    bf16*  u2     = (bf16*)(ws + OFF_U2);
    float* cnorm  = (float*)(ws + OFF_CNRM);
    float* bfuse  = (float*)(ws + OFF_BFUS);
    float* commit = (float*)(ws + OFF_STAT);
    double* gram  = (double*)(ws + OFF_STAT + 8);
    float* meanA  = (float*)(ws + OFF_STAT + 64);
    float* part   = (float*)(ws + OFF_PART);

    float* out_f   = (float*)d_out;
    float* idx_out = out_f + (size_t)8192 * 4096;
    float* scal    = idx_out + (size_t)8192 * 3;

    hipMemsetAsync(ws + OFF_STAT, 0, 2048, stream);

    const dim3 tb(32, 8);
    wtrans_hilo<<<dim3(16, 128), tb, 0, stream>>>(Wd1, Wd1s, 4096, 512);
    wtrans_split3<<<dim3(8, 16),   tb, 0, stream>>>(Wd2, Wd2s, 512, 256);
    wtrans_bf16<<<dim3(8, 4),      tb, 0, stream>>>(Wu1, Wu1T, 128, 256);
    wtrans_bf16<<<dim3(16, 8),     tb, 0, stream>>>(Wu2, Wu2T, 256, 512);
    wtrans_bf16<<<dim3(128, 16),   tb, 0, stream>>>(Wu3, Wu3T, 512, 4096);
    cnorm_kernel<<<3, 256, 0, stream>>>(cb, cnorm);
    wfuse_kernel<<<128, 256, 0, stream>>>(Wd3, bd3, Win, bin_, WfuseS, bfuse);

    // down MLP (split bf16, ~f32 accuracy) ending directly in xe = latent@Win+...
    gemm1_x3<<<dim3(4, 64, 4), 256, 0, stream>>>(x, Wd1s, part);
    h1_epi<<<4096, 256, 0, stream>>>(part, bd1, h1s);
    gemm_bt<1, 1, 64><<<dim3(2, 128), 256, 0, stream>>>(h1s, Wd2s, bd2, h2s, 8192, 256, 1536);
    gemm_bt<0, 0, 64><<<dim3(1, 128), 256, 0, stream>>>(h2s, WfuseS, bfuse, xe, 8192, 128, 768);

    vq2_kernel<<<768, 256, 0, stream>>>(xe, cb, cnorm, Wout, bout, qemb, idx_out, commit);
    rlgram_kernel<<<256, 256, 0, stream>>>(qemb, rl, meanA, gram);
    final_kernel<<<1, 64, 0, stream>>>(commit, gram, meanA, scal);

    // up MLP: plain bf16 compute, f32 recon out
    gemm_bt<2, 1, 64><<<dim3(2, 128),  256, 0, stream>>>(rl, Wu1T, bu1, u1,    8192, 256,  128);
    gemm_bt<2, 1, 64><<<dim3(4, 128),  256, 0, stream>>>(u1, Wu2T, bu2, u2,    8192, 512,  256);
    gemm_bt<3, 0, 128><<<dim3(32, 64), 256, 0, stream>>>(u2, Wu3T, bu3, out_f, 8192, 4096, 512);

    (void)in_sizes; (void)n_in; (void)out_size; (void)ws_size;
}